// Round 7
// baseline (274.828 us; speedup 1.0000x reference)
//
#include <hip/hip_runtime.h>
#include <stdint.h>

// SparseAttention MI355X bf16-MFMA pipeline. Output f32.
// QKV row-major [B*S][2304] bf16; V^T [B*H][64][2048] bf16 (vprep).
// Attention: CONSTANT-SHIFT softmax (p=exp(s-8), scores |s|<~3) -> partials
// over key-chunks are pure sums -> split-K for global heads + combine pass.
// R7: attn back to R5 structure (64 q-rows, 2208 blocks — latency-bound, so
// parallelism > MFMA density; R6's 128-row variant regressed 55->75 us) plus
// REGISTER PREFETCH of next K/V tile (hides global-load latency behind the
// QK+softmax+PV compute of the current tile).
// MFMA 16x16x32 bf16 layouts (HW-verified): A[m=lane&15][k=quad*8+j],
// B[k=quad*8+j][n=lane&15], C/D col=lane&15 row=quad*4+reg.

#define NH 12
#define SQ 2048

typedef __bf16 bf16x8 __attribute__((ext_vector_type(8)));
typedef float f32x4 __attribute__((ext_vector_type(4)));

#define GLOAD_LDS16(g, l)                                                      \
  __builtin_amdgcn_global_load_lds(                                            \
      (__attribute__((address_space(1))) void*)(g),                            \
      (__attribute__((address_space(3))) void*)(l), 16, 0, 0)

__device__ __forceinline__ unsigned short bfbits(float f) {
  __bf16 h = (__bf16)f;
  return *(unsigned short*)&h;
}

// ---------------- prep: x->bf16 + both weight transposes (1 kernel) --------
__global__ __launch_bounds__(256) void prep(
    const float* __restrict__ x, unsigned short* __restrict__ xb,
    const float* __restrict__ w_attn, unsigned short* __restrict__ wattnT,
    const float* __restrict__ w_proj, unsigned short* __restrict__ wprojT) {
  const int bid = blockIdx.x, t = threadIdx.x;
  if (bid < 512) {                 // convert x: 8192*768 floats
    const int n4 = 8192 * 768 / 4;
    for (int i = bid * 256 + t; i < n4; i += 512 * 256) {
      float4 v = ((const float4*)x)[i];
      ((ushort4*)xb)[i] = make_ushort4(bfbits(v.x), bfbits(v.y), bfbits(v.z), bfbits(v.w));
    }
    return;
  }
  __shared__ float tile[32][33];
  const float* in; unsigned short* out; int K, N, tl;
  if (bid < 512 + 72 * 24) { in = w_attn; out = wattnT; K = 768; N = 2304; tl = bid - 512; }
  else                     { in = w_proj; out = wprojT; K = 768; N = 768;  tl = bid - 512 - 72 * 24; }
  const int tpr = N / 32;
  const int n0 = (tl % tpr) * 32, k0 = (tl / tpr) * 32;
  const int tx = t & 31, ty = t >> 5;
  for (int r = ty; r < 32; r += 8) tile[r][tx] = in[(size_t)(k0 + r) * N + n0 + tx];
  __syncthreads();
  for (int r = ty; r < 32; r += 8) out[(size_t)(n0 + r) * K + k0 + tx] = bfbits(tile[tx][r]);
}

// ---------------- vprep: V transpose + gcol gather (1 kernel) ----------------
__global__ __launch_bounds__(256) void vprep(const unsigned short* __restrict__ QKV,
                                             unsigned short* __restrict__ Vtb,
                                             unsigned short* __restrict__ Kg,
                                             unsigned short* __restrict__ VgT,
                                             int* __restrict__ gidx) {
  const int id = blockIdx.x, t = threadIdx.x;
  if (id < 1536) {                 // vtrans
    const int bh = id >> 5, b = bh / NH, h = bh % NH;
    const int s0 = (id & 31) * 64;
    __shared__ unsigned short T[64][72];
    const int r = t >> 2, c0 = (t & 3) * 16;
    const size_t src = (size_t)(b * SQ + s0 + r) * 2304 + 1536 + h * 64 + c0;
    *(uint4*)&T[r][c0]     = *(const uint4*)&QKV[src];
    *(uint4*)&T[r][c0 + 8] = *(const uint4*)&QKV[src + 8];
    __syncthreads();
    unsigned short pk[16];
#pragma unroll
    for (int z = 0; z < 16; ++z) pk[z] = T[c0 + z][r];
    size_t dst = (size_t)bh * 131072 + (size_t)r * 2048 + s0 + c0;
    *(uint4*)&Vtb[dst]     = *(uint4*)&pk[0];
    *(uint4*)&Vtb[dst + 8] = *(uint4*)&pk[8];
    return;
  }
  const int g = id - 1536;         // gather: 16 bh * 8 chunks
  const int bh = g >> 3, y = g & 7;
  const int b = bh >> 2, h = 8 + (bh & 3);
  if (g == 0) {
    int c = t;
    gidx[c] = (c < 203) ? (int)((double)c * (2047.0 / 203.0)) : ((c == 203) ? 2047 : -1);
  }
  {  // Kg rows from qkvb K-section
    int c = t, ch = y;
    int col = (c < 203) ? (int)((double)c * (2047.0 / 203.0)) : ((c == 203) ? 2047 : -1);
    uint4 v = {0u, 0u, 0u, 0u};
    if (col >= 0) v = *(const uint4*)&QKV[(size_t)(b * SQ + col) * 2304 + 768 + h * 64 + ch * 8];
    *(uint4*)&Kg[((size_t)bh * 256 + c) * 64 + ch * 8] = v;
  }
  {  // VgT directly from qkvb V-section (transpose gather)
    int d = t >> 2;
    int cb = (t & 3) * 64 + y * 8;
    for (int cc = 0; cc < 8; ++cc) {
      int c = cb + cc;
      int col = (c < 203) ? (int)((double)c * (2047.0 / 203.0)) : ((c == 203) ? 2047 : -1);
      unsigned short v = 0;
      if (col >= 0) v = QKV[(size_t)(b * SQ + col) * 2304 + 1536 + h * 64 + d];
      VgT[((size_t)bh * 64 + d) * 256 + c] = v;
    }
  }
}

// ---------------- GEMM mainloop (BM=BN=128, BK=32, async LDS DMA) ----------
__device__ __forceinline__ void gemm_mainloop(
    const unsigned short* __restrict__ A, const unsigned short* __restrict__ BT,
    int m0, int n0, int tid,
    unsigned short* As, unsigned short* Bs,   // 128 x 32 bf16, UNPADDED
    f32x4 acc[4][4]) {
  const int lane = tid & 63, wave = tid >> 6;
  const int wm = wave >> 1, wn = wave & 1;
  const int ln = lane & 15, quad = lane >> 4;
  const int arow = wave * 16 + (lane >> 2);
  const int acol = (lane & 3) * 8;

#pragma unroll
  for (int mi = 0; mi < 4; ++mi)
#pragma unroll
    for (int ni = 0; ni < 4; ++ni) acc[mi][ni] = (f32x4){0.f, 0.f, 0.f, 0.f};

  for (int kt = 0; kt < 24; ++kt) {
    const int k0 = kt * 32;
    __syncthreads();
#pragma unroll
    for (int p = 0; p < 2; ++p) {
      GLOAD_LDS16(A  + (size_t)(m0 + p * 64 + arow) * 768 + k0 + acol,
                  &As[(p * 64 + wave * 16) * 32]);
      GLOAD_LDS16(BT + (size_t)(n0 + p * 64 + arow) * 768 + k0 + acol,
                  &Bs[(p * 64 + wave * 16) * 32]);
    }
    __syncthreads();
    bf16x8 aF[4], bF[4];
#pragma unroll
    for (int mi = 0; mi < 4; ++mi) aF[mi] = *(const bf16x8*)&As[(wm * 64 + mi * 16 + ln) * 32 + quad * 8];
#pragma unroll
    for (int ni = 0; ni < 4; ++ni) bF[ni] = *(const bf16x8*)&Bs[(wn * 64 + ni * 16 + ln) * 32 + quad * 8];
#pragma unroll
    for (int mi = 0; mi < 4; ++mi)
#pragma unroll
      for (int ni = 0; ni < 4; ++ni)
        acc[mi][ni] = __builtin_amdgcn_mfma_f32_16x16x32_bf16(aF[mi], bF[ni], acc[mi][ni], 0, 0, 0);
  }
}

// ---------------- QKV GEMM: row-major bf16 out ----------------
__global__ __launch_bounds__(256) void qkv_gemm(
    const unsigned short* __restrict__ Xb, const unsigned short* __restrict__ WT,
    const float* __restrict__ bias, unsigned short* __restrict__ Out) {
  __shared__ __attribute__((aligned(16))) unsigned short As[128 * 32];
  __shared__ __attribute__((aligned(16))) unsigned short Bs[128 * 32];
  f32x4 acc[4][4];
  const int m0 = blockIdx.y * 128, n0 = blockIdx.x * 128;
  const int tid = threadIdx.x;
  gemm_mainloop(Xb, WT, m0, n0, tid, As, Bs, acc);
  const int lane = tid & 63, wave = tid >> 6;
  const int wm = wave >> 1, wn = wave & 1, ln = lane & 15, quad = lane >> 4;
#pragma unroll
  for (int mi = 0; mi < 4; ++mi)
#pragma unroll
    for (int ni = 0; ni < 4; ++ni) {
      int n = n0 + wn * 64 + ni * 16 + ln;
      float bs = bias[n];
#pragma unroll
      for (int rg = 0; rg < 4; ++rg) {
        int m = m0 + wm * 64 + mi * 16 + quad * 4 + rg;
        Out[(size_t)m * 2304 + n] = bfbits(acc[mi][ni][rg] + bs);
      }
    }
}

// ---------------- Proj GEMM: fp32 out ----------------
__global__ __launch_bounds__(256) void proj_gemm(
    const unsigned short* __restrict__ Ab, const unsigned short* __restrict__ WT,
    const float* __restrict__ bias, float* __restrict__ Out) {
  __shared__ __attribute__((aligned(16))) unsigned short As[128 * 32];
  __shared__ __attribute__((aligned(16))) unsigned short Bs[128 * 32];
  f32x4 acc[4][4];
  const int m0 = blockIdx.y * 128, n0 = blockIdx.x * 128;
  const int tid = threadIdx.x;
  gemm_mainloop(Ab, WT, m0, n0, tid, As, Bs, acc);
  const int lane = tid & 63, wave = tid >> 6;
  const int wm = wave >> 1, wn = wave & 1, ln = lane & 15, quad = lane >> 4;
#pragma unroll
  for (int mi = 0; mi < 4; ++mi)
#pragma unroll
    for (int ni = 0; ni < 4; ++ni)
#pragma unroll
      for (int rg = 0; rg < 4; ++rg) {
        int m = m0 + wm * 64 + mi * 16 + quad * 4 + rg;
        int n = n0 + wn * 64 + ni * 16 + ln;
        Out[(size_t)m * 768 + n] = acc[mi][ni][rg] + bias[n];
      }
}

// ---------------- Flash attention (R5 structure + register prefetch) --------
// Grid 2208: [0,1184) global-head parts (<=13 tiles), [1184,2208) local (<=5).
// Global parts: causal kb in [9p, min(9p+8,qb)]; part 0 also does 4 gcol
// tiles. Partials (bf16 O, f32 l) -> combine kernel. Locals write direct.
// Next tile's K/V prefetched into registers while current tile computes.
__global__ __launch_bounds__(256, 6) void attn_kernel(
    const unsigned short* __restrict__ QKV,   // [8192][2304]
    const unsigned short* __restrict__ Vtb,   // [48][64][2048]
    const unsigned short* __restrict__ Kg, const unsigned short* __restrict__ VgT,
    const int* __restrict__ gidx,
    unsigned short* __restrict__ AOut,        // [8192][768]
    unsigned short* __restrict__ Opart,       // [2048][4096] bf16
    float* __restrict__ Lpart) {              // [2048][64]
  __shared__ __attribute__((aligned(16))) unsigned short Ks[64 * 72];  // also P
  __shared__ __attribute__((aligned(16))) unsigned short Vs[64 * 72];

  const int gid = blockIdx.x;
  int b, h, qb, kb_begin, kb_end, slot = 0;
  bool do_g = false;
  if (gid < 1184) {
    int bh = gid / 74, rem = gid % 74;
    b = bh >> 2; h = 8 + (bh & 3);
    int part;
    if (rem < 9)       { qb = rem; part = 0; }
    else if (rem < 27) { int z = rem - 9;  qb = 9 + (z >> 1);  part = z & 1; }
    else if (rem < 54) { int z = rem - 27; int q3 = z / 3; qb = 18 + q3; part = z - 3 * q3; }
    else               { int z = rem - 54; qb = 27 + (z >> 2); part = z & 3; }
    kb_begin = part * 9;
    kb_end = min(part * 9 + 8, qb);
    do_g = (part == 0);
    slot = ((b * 4 + (h - 8)) * 32 + qb) * 4 + part;
  } else {
    int lid = gid - 1184;
    int bh = lid >> 5; b = bh >> 3; h = bh & 7; qb = lid & 31;
    kb_begin = (qb > 4) ? qb - 4 : 0; kb_end = qb;
  }
  const int qb0 = qb * 64;
  const bool is_local = (h < 8);
  const int tid = threadIdx.x, lane = tid & 63, wave = tid >> 6;
  const int ln = lane & 15, quad = lane >> 4;
  const int bh48 = b * NH + h;
  const int bhg = (b << 2) | (h & 3);

  const size_t qoff = (size_t)(b * SQ + qb0 + wave * 16 + ln) * 2304 + h * 64;
  bf16x8 qA0 = *(const bf16x8*)&QKV[qoff + quad * 8];
  bf16x8 qA1 = *(const bf16x8*)&QKV[qoff + 32 + quad * 8];

  bf16x8 onesF;
#pragma unroll
  for (int z = 0; z < 8; ++z) onesF[z] = (__bf16)1.0f;

  f32x4 o[4];
  f32x4 ls = (f32x4){0.f, 0.f, 0.f, 0.f};
#pragma unroll
  for (int dt = 0; dt < 4; ++dt) o[dt] = (f32x4){0.f, 0.f, 0.f, 0.f};

  const int nc = kb_end - kb_begin + 1;
  const int ntiles = nc + (do_g ? 4 : 0);
  const int irow = qb0 + wave * 16 + quad * 4;  // + rg
  const int iw = qb0 + wave * 16;
  const int sr = tid >> 3, sch = tid & 7;

  // -------- register prefetch of tile t's K/V staging chunks --------
  uint4 kpre[2], vpre[2];
  auto prefetch = [&](int t) {
    const bool gph = (t >= nc);
    if (!gph) {
      const int kstart = (kb_begin + t) * 64;
#pragma unroll
      for (int p = 0; p < 2; ++p) {
        int row = p * 32 + sr;
        kpre[p] = *(const uint4*)&QKV[(size_t)(b * SQ + kstart + row) * 2304 + 768 + h * 64 + sch * 8];
        vpre[p] = *(const uint4*)&Vtb[(size_t)bh48 * 131072 + (size_t)row * 2048 + kstart + sch * 8];
      }
    } else {
      const int kg0 = (t - nc) * 64;
#pragma unroll
      for (int p = 0; p < 2; ++p) {
        int row = p * 32 + sr;
        kpre[p] = *(const uint4*)&Kg[((size_t)bhg * 256 + kg0 + row) * 64 + sch * 8];
        vpre[p] = *(const uint4*)&VgT[((size_t)bhg * 64 + row) * 256 + kg0 + sch * 8];
      }
    }
  };
  prefetch(0);

  for (int t = 0; t < ntiles; ++t) {
    const bool gph = (t >= nc);
    const int kstart = gph ? 0 : (kb_begin + t) * 64;
    const int kg0 = gph ? (t - nc) * 64 : 0;
    __syncthreads();  // prev iter's P/Vs reads done before restage
#pragma unroll
    for (int p = 0; p < 2; ++p) {
      int row = p * 32 + sr;
      *(uint4*)&Ks[row * 72 + sch * 8] = kpre[p];
      *(uint4*)&Vs[row * 72 + sch * 8] = vpre[p];
    }
    __syncthreads();
    if (t + 1 < ntiles) prefetch(t + 1);  // overlaps with compute below

    float sc[4][4];
    const bool full = !gph && (kstart + 63 <= iw) && (!is_local || kstart >= iw - 241);
#pragma unroll
    for (int nt = 0; nt < 4; ++nt) {
      bf16x8 kF0 = *(const bf16x8*)&Ks[(nt * 16 + ln) * 72 + quad * 8];
      bf16x8 kF1 = *(const bf16x8*)&Ks[(nt * 16 + ln) * 72 + 32 + quad * 8];
      f32x4 c = (f32x4){0.f, 0.f, 0.f, 0.f};
      c = __builtin_amdgcn_mfma_f32_16x16x32_bf16(qA0, kF0, c, 0, 0, 0);
      c = __builtin_amdgcn_mfma_f32_16x16x32_bf16(qA1, kF1, c, 0, 0, 0);
      if (full) {
#pragma unroll
        for (int rg = 0; rg < 4; ++rg) sc[nt][rg] = c[rg] * 0.125f - 8.f;
      } else if (!gph) {
        int j = kstart + nt * 16 + ln;
#pragma unroll
        for (int rg = 0; rg < 4; ++rg) {
          int i = irow + rg;
          bool ok = is_local ? (j >= i - 256 && j <= i) : (j <= i);
          sc[nt][rg] = ok ? (c[rg] * 0.125f - 8.f) : -1e9f;
        }
      } else {
        int jg = gidx[kg0 + nt * 16 + ln];
#pragma unroll
        for (int rg = 0; rg < 4; ++rg) {
          bool ok = jg > (irow + rg);
          sc[nt][rg] = ok ? (c[rg] * 0.125f - 8.f) : -1e9f;
        }
      }
    }
    __syncthreads();  // all waves done reading Ks -> reuse as P

    __bf16* P = (__bf16*)Ks;
#pragma unroll
    for (int rg = 0; rg < 4; ++rg) {
      int prow = (wave * 16 + quad * 4 + rg) * 72;
#pragma unroll
      for (int nt = 0; nt < 4; ++nt)
        P[prow + nt * 16 + ln] = (__bf16)__expf(sc[nt][rg]);
    }
    // same-wave LDS RAW (DS pipe in-order per wave) — no barrier needed
    bf16x8 pF0 = *(const bf16x8*)&Ks[(wave * 16 + ln) * 72 + quad * 8];
    bf16x8 pF1 = *(const bf16x8*)&Ks[(wave * 16 + ln) * 72 + 32 + quad * 8];
    ls = __builtin_amdgcn_mfma_f32_16x16x32_bf16(pF0, onesF, ls, 0, 0, 0);
    ls = __builtin_amdgcn_mfma_f32_16x16x32_bf16(pF1, onesF, ls, 0, 0, 0);
#pragma unroll
    for (int dt = 0; dt < 4; ++dt) {
      bf16x8 vF0 = *(const bf16x8*)&Vs[(dt * 16 + ln) * 72 + quad * 8];
      bf16x8 vF1 = *(const bf16x8*)&Vs[(dt * 16 + ln) * 72 + 32 + quad * 8];
      o[dt] = __builtin_amdgcn_mfma_f32_16x16x32_bf16(pF0, vF0, o[dt], 0, 0, 0);
      o[dt] = __builtin_amdgcn_mfma_f32_16x16x32_bf16(pF1, vF1, o[dt], 0, 0, 0);
    }
  }

  if (gid >= 1184) {  // local: direct write
#pragma unroll
    for (int dt = 0; dt < 4; ++dt)
#pragma unroll
      for (int rg = 0; rg < 4; ++rg) {
        int row = b * SQ + qb0 + wave * 16 + quad * 4 + rg;
        int e = h * 64 + dt * 16 + ln;
        AOut[(size_t)row * 768 + e] = bfbits(o[dt][rg] / ls[rg]);
      }
  } else {  // global: partials
#pragma unroll
    for (int dt = 0; dt < 4; ++dt)
#pragma unroll
      for (int rg = 0; rg < 4; ++rg) {
        int row = wave * 16 + quad * 4 + rg;
        Opart[(size_t)slot * 4096 + row * 64 + dt * 16 + ln] = bfbits(o[dt][rg]);
      }
    if (ln == 0) {
#pragma unroll
      for (int rg = 0; rg < 4; ++rg)
        Lpart[(size_t)slot * 64 + wave * 16 + quad * 4 + rg] = ls[rg];
    }
  }
}

// ---------------- combine split-K partials (global heads) ----------------
__global__ __launch_bounds__(256) void combine_parts(
    const unsigned short* __restrict__ Opart, const float* __restrict__ Lpart,
    unsigned short* __restrict__ AOut) {
  const int bid = blockIdx.x;        // 512 = 16 bh * 32 qb
  const int bh = bid >> 5, qb = bid & 31;
  const int b = bh >> 2, h = 8 + (bh & 3);
  const int np = qb / 9 + 1;
  const int t = threadIdx.x, r = t >> 2, c0 = (t & 3) * 16;
  const int slot0 = (bh * 32 + qb) * 4;
  float acc[16];
#pragma unroll
  for (int z = 0; z < 16; ++z) acc[z] = 0.f;
  float l = 0.f;
  for (int p = 0; p < np; ++p) {
    const unsigned short* src = &Opart[(size_t)(slot0 + p) * 4096 + r * 64 + c0];
    bf16x8 v0 = *(const bf16x8*)&src[0];
    bf16x8 v1 = *(const bf16x8*)&src[8];
#pragma unroll
    for (int z = 0; z < 8; ++z) { acc[z] += (float)v0[z]; acc[8 + z] += (float)v1[z]; }
    l += Lpart[(size_t)(slot0 + p) * 64 + r];
  }
  float inv = 1.f / l;
  unsigned short pk[16];
#pragma unroll
  for (int z = 0; z < 16; ++z) pk[z] = bfbits(acc[z] * inv);
  size_t dst = (size_t)(b * SQ + qb * 64 + r) * 768 + h * 64 + c0;
  *(uint4*)&AOut[dst]     = *(uint4*)&pk[0];
  *(uint4*)&AOut[dst + 8] = *(uint4*)&pk[8];
}

// ---------------- launch ----------------
extern "C" void kernel_launch(void* const* d_in, const int* in_sizes, int n_in,
                              void* d_out, int out_size, void* d_ws, size_t ws_size,
                              hipStream_t stream) {
  const float* x      = (const float*)d_in[0];
  const float* w_attn = (const float*)d_in[1];
  const float* b_attn = (const float*)d_in[2];
  const float* w_proj = (const float*)d_in[3];
  const float* b_proj = (const float*)d_in[4];
  float* out = (float*)d_out;

  char* ws = (char*)d_ws;
  size_t off = 0;
  auto alloc = [&](size_t bytes) {
    void* p = ws + off;
    off += (bytes + 255) & ~(size_t)255;
    return p;
  };
  unsigned short* xb     = (unsigned short*)alloc((size_t)8192 * 768 * 2);   // reused as attn buf
  unsigned short* wattnT = (unsigned short*)alloc((size_t)2304 * 768 * 2);
  unsigned short* wprojT = (unsigned short*)alloc((size_t)768 * 768 * 2);
  unsigned short* qkvb   = (unsigned short*)alloc((size_t)8192 * 2304 * 2);
  unsigned short* Vtb    = (unsigned short*)alloc((size_t)48 * 64 * 2048 * 2);
  unsigned short* Kgb    = (unsigned short*)alloc((size_t)16 * 256 * 64 * 2);
  unsigned short* VgTb   = (unsigned short*)alloc((size_t)16 * 64 * 256 * 2);
  int* gidxb             = (int*)alloc((size_t)256 * 4);
  unsigned short* Opartb = (unsigned short*)alloc((size_t)2048 * 4096 * 2);
  float* Lpartb          = (float*)alloc((size_t)2048 * 64 * 4);
  unsigned short* attnb  = xb;  // xb dead after qkv_gemm

  prep<<<dim3(512 + 72 * 24 + 24 * 24), dim3(256), 0, stream>>>(
      x, xb, w_attn, wattnT, w_proj, wprojT);
  qkv_gemm<<<dim3(18, 64), dim3(256), 0, stream>>>(xb, wattnT, b_attn, qkvb);
  vprep<<<dim3(1536 + 128), dim3(256), 0, stream>>>(qkvb, Vtb, Kgb, VgTb, gidxb);
  attn_kernel<<<dim3(2208), dim3(256), 0, stream>>>(qkvb, Vtb, Kgb, VgTb, gidxb,
                                                    attnb, Opartb, Lpartb);
  combine_parts<<<dim3(512), dim3(256), 0, stream>>>(Opartb, Lpartb, attnb);
  proj_gemm<<<dim3(6, 64), dim3(256), 0, stream>>>(attnb, wprojT, b_proj, out);
}

// Round 8
// 243.473 us; speedup vs baseline: 1.1288x; 1.1288x over previous
//
#include <hip/hip_runtime.h>
#include <stdint.h>

// SparseAttention MI355X bf16-MFMA pipeline. Output f32.
// QKV row-major [B*S][2304] bf16; V^T [B*H][64][2048] bf16 (vprep).
// Attention: CONSTANT-SHIFT softmax (p=exp(s-8), scores |s|<~3) -> partials
// over key-chunks are pure sums -> split-K for global heads + combine pass.
// R8: R5 attn structure (64 q-rows, 2208 blocks) + register prefetch of next
// K/V tile implemented as NAMED uint4 variables, straight-line (R7's
// lambda+array version went to scratch: +273MB WRITE_SIZE, 110us).
// MFMA 16x16x32 bf16 layouts (HW-verified): A[m=lane&15][k=quad*8+j],
// B[k=quad*8+j][n=lane&15], C/D col=lane&15 row=quad*4+reg.

#define NH 12
#define SQ 2048

typedef __bf16 bf16x8 __attribute__((ext_vector_type(8)));
typedef float f32x4 __attribute__((ext_vector_type(4)));

#define GLOAD_LDS16(g, l)                                                      \
  __builtin_amdgcn_global_load_lds(                                            \
      (__attribute__((address_space(1))) void*)(g),                            \
      (__attribute__((address_space(3))) void*)(l), 16, 0, 0)

__device__ __forceinline__ unsigned short bfbits(float f) {
  __bf16 h = (__bf16)f;
  return *(unsigned short*)&h;
}

// ---------------- prep: x->bf16 + both weight transposes (1 kernel) --------
__global__ __launch_bounds__(256) void prep(
    const float* __restrict__ x, unsigned short* __restrict__ xb,
    const float* __restrict__ w_attn, unsigned short* __restrict__ wattnT,
    const float* __restrict__ w_proj, unsigned short* __restrict__ wprojT) {
  const int bid = blockIdx.x, t = threadIdx.x;
  if (bid < 512) {                 // convert x: 8192*768 floats
    const int n4 = 8192 * 768 / 4;
    for (int i = bid * 256 + t; i < n4; i += 512 * 256) {
      float4 v = ((const float4*)x)[i];
      ((ushort4*)xb)[i] = make_ushort4(bfbits(v.x), bfbits(v.y), bfbits(v.z), bfbits(v.w));
    }
    return;
  }
  __shared__ float tile[32][33];
  const float* in; unsigned short* out; int K, N, tl;
  if (bid < 512 + 72 * 24) { in = w_attn; out = wattnT; K = 768; N = 2304; tl = bid - 512; }
  else                     { in = w_proj; out = wprojT; K = 768; N = 768;  tl = bid - 512 - 72 * 24; }
  const int tpr = N / 32;
  const int n0 = (tl % tpr) * 32, k0 = (tl / tpr) * 32;
  const int tx = t & 31, ty = t >> 5;
  for (int r = ty; r < 32; r += 8) tile[r][tx] = in[(size_t)(k0 + r) * N + n0 + tx];
  __syncthreads();
  for (int r = ty; r < 32; r += 8) out[(size_t)(n0 + r) * K + k0 + tx] = bfbits(tile[tx][r]);
}

// ---------------- vprep: V transpose + gcol gather (1 kernel) ----------------
__global__ __launch_bounds__(256) void vprep(const unsigned short* __restrict__ QKV,
                                             unsigned short* __restrict__ Vtb,
                                             unsigned short* __restrict__ Kg,
                                             unsigned short* __restrict__ VgT,
                                             int* __restrict__ gidx) {
  const int id = blockIdx.x, t = threadIdx.x;
  if (id < 1536) {                 // vtrans
    const int bh = id >> 5, b = bh / NH, h = bh % NH;
    const int s0 = (id & 31) * 64;
    __shared__ unsigned short T[64][72];
    const int r = t >> 2, c0 = (t & 3) * 16;
    const size_t src = (size_t)(b * SQ + s0 + r) * 2304 + 1536 + h * 64 + c0;
    *(uint4*)&T[r][c0]     = *(const uint4*)&QKV[src];
    *(uint4*)&T[r][c0 + 8] = *(const uint4*)&QKV[src + 8];
    __syncthreads();
    unsigned short pk[16];
#pragma unroll
    for (int z = 0; z < 16; ++z) pk[z] = T[c0 + z][r];
    size_t dst = (size_t)bh * 131072 + (size_t)r * 2048 + s0 + c0;
    *(uint4*)&Vtb[dst]     = *(uint4*)&pk[0];
    *(uint4*)&Vtb[dst + 8] = *(uint4*)&pk[8];
    return;
  }
  const int g = id - 1536;         // gather: 16 bh * 8 chunks
  const int bh = g >> 3, y = g & 7;
  const int b = bh >> 2, h = 8 + (bh & 3);
  if (g == 0) {
    int c = t;
    gidx[c] = (c < 203) ? (int)((double)c * (2047.0 / 203.0)) : ((c == 203) ? 2047 : -1);
  }
  {  // Kg rows from qkvb K-section
    int c = t, ch = y;
    int col = (c < 203) ? (int)((double)c * (2047.0 / 203.0)) : ((c == 203) ? 2047 : -1);
    uint4 v = {0u, 0u, 0u, 0u};
    if (col >= 0) v = *(const uint4*)&QKV[(size_t)(b * SQ + col) * 2304 + 768 + h * 64 + ch * 8];
    *(uint4*)&Kg[((size_t)bh * 256 + c) * 64 + ch * 8] = v;
  }
  {  // VgT directly from qkvb V-section (transpose gather)
    int d = t >> 2;
    int cb = (t & 3) * 64 + y * 8;
    for (int cc = 0; cc < 8; ++cc) {
      int c = cb + cc;
      int col = (c < 203) ? (int)((double)c * (2047.0 / 203.0)) : ((c == 203) ? 2047 : -1);
      unsigned short v = 0;
      if (col >= 0) v = QKV[(size_t)(b * SQ + col) * 2304 + 1536 + h * 64 + d];
      VgT[((size_t)bh * 64 + d) * 256 + c] = v;
    }
  }
}

// ---------------- GEMM mainloop (BM=BN=128, BK=32, async LDS DMA) ----------
__device__ __forceinline__ void gemm_mainloop(
    const unsigned short* __restrict__ A, const unsigned short* __restrict__ BT,
    int m0, int n0, int tid,
    unsigned short* As, unsigned short* Bs,   // 128 x 32 bf16, UNPADDED
    f32x4 acc[4][4]) {
  const int lane = tid & 63, wave = tid >> 6;
  const int wm = wave >> 1, wn = wave & 1;
  const int ln = lane & 15, quad = lane >> 4;
  const int arow = wave * 16 + (lane >> 2);
  const int acol = (lane & 3) * 8;

#pragma unroll
  for (int mi = 0; mi < 4; ++mi)
#pragma unroll
    for (int ni = 0; ni < 4; ++ni) acc[mi][ni] = (f32x4){0.f, 0.f, 0.f, 0.f};

  for (int kt = 0; kt < 24; ++kt) {
    const int k0 = kt * 32;
    __syncthreads();
#pragma unroll
    for (int p = 0; p < 2; ++p) {
      GLOAD_LDS16(A  + (size_t)(m0 + p * 64 + arow) * 768 + k0 + acol,
                  &As[(p * 64 + wave * 16) * 32]);
      GLOAD_LDS16(BT + (size_t)(n0 + p * 64 + arow) * 768 + k0 + acol,
                  &Bs[(p * 64 + wave * 16) * 32]);
    }
    __syncthreads();
    bf16x8 aF[4], bF[4];
#pragma unroll
    for (int mi = 0; mi < 4; ++mi) aF[mi] = *(const bf16x8*)&As[(wm * 64 + mi * 16 + ln) * 32 + quad * 8];
#pragma unroll
    for (int ni = 0; ni < 4; ++ni) bF[ni] = *(const bf16x8*)&Bs[(wn * 64 + ni * 16 + ln) * 32 + quad * 8];
#pragma unroll
    for (int mi = 0; mi < 4; ++mi)
#pragma unroll
      for (int ni = 0; ni < 4; ++ni)
        acc[mi][ni] = __builtin_amdgcn_mfma_f32_16x16x32_bf16(aF[mi], bF[ni], acc[mi][ni], 0, 0, 0);
  }
}

// ---------------- QKV GEMM: row-major bf16 out ----------------
__global__ __launch_bounds__(256) void qkv_gemm(
    const unsigned short* __restrict__ Xb, const unsigned short* __restrict__ WT,
    const float* __restrict__ bias, unsigned short* __restrict__ Out) {
  __shared__ __attribute__((aligned(16))) unsigned short As[128 * 32];
  __shared__ __attribute__((aligned(16))) unsigned short Bs[128 * 32];
  f32x4 acc[4][4];
  const int m0 = blockIdx.y * 128, n0 = blockIdx.x * 128;
  const int tid = threadIdx.x;
  gemm_mainloop(Xb, WT, m0, n0, tid, As, Bs, acc);
  const int lane = tid & 63, wave = tid >> 6;
  const int wm = wave >> 1, wn = wave & 1, ln = lane & 15, quad = lane >> 4;
#pragma unroll
  for (int mi = 0; mi < 4; ++mi)
#pragma unroll
    for (int ni = 0; ni < 4; ++ni) {
      int n = n0 + wn * 64 + ni * 16 + ln;
      float bs = bias[n];
#pragma unroll
      for (int rg = 0; rg < 4; ++rg) {
        int m = m0 + wm * 64 + mi * 16 + quad * 4 + rg;
        Out[(size_t)m * 2304 + n] = bfbits(acc[mi][ni][rg] + bs);
      }
    }
}

// ---------------- Proj GEMM: fp32 out ----------------
__global__ __launch_bounds__(256) void proj_gemm(
    const unsigned short* __restrict__ Ab, const unsigned short* __restrict__ WT,
    const float* __restrict__ bias, float* __restrict__ Out) {
  __shared__ __attribute__((aligned(16))) unsigned short As[128 * 32];
  __shared__ __attribute__((aligned(16))) unsigned short Bs[128 * 32];
  f32x4 acc[4][4];
  const int m0 = blockIdx.y * 128, n0 = blockIdx.x * 128;
  const int tid = threadIdx.x;
  gemm_mainloop(Ab, WT, m0, n0, tid, As, Bs, acc);
  const int lane = tid & 63, wave = tid >> 6;
  const int wm = wave >> 1, wn = wave & 1, ln = lane & 15, quad = lane >> 4;
#pragma unroll
  for (int mi = 0; mi < 4; ++mi)
#pragma unroll
    for (int ni = 0; ni < 4; ++ni)
#pragma unroll
      for (int rg = 0; rg < 4; ++rg) {
        int m = m0 + wm * 64 + mi * 16 + quad * 4 + rg;
        int n = n0 + wn * 64 + ni * 16 + ln;
        Out[(size_t)m * 768 + n] = acc[mi][ni][rg] + bias[n];
      }
}

// ---------------- Flash attention (R5 + named-register prefetch) -----------
// Grid 2208: [0,1184) global-head parts (<=13 tiles), [1184,2208) local (<=5).
__global__ __launch_bounds__(256, 6) void attn_kernel(
    const unsigned short* __restrict__ QKV,   // [8192][2304]
    const unsigned short* __restrict__ Vtb,   // [48][64][2048]
    const unsigned short* __restrict__ Kg, const unsigned short* __restrict__ VgT,
    const int* __restrict__ gidx,
    unsigned short* __restrict__ AOut,        // [8192][768]
    unsigned short* __restrict__ Opart,       // [2048][4096] bf16
    float* __restrict__ Lpart) {              // [2048][64]
  __shared__ __attribute__((aligned(16))) unsigned short Ks[64 * 72];  // also P
  __shared__ __attribute__((aligned(16))) unsigned short Vs[64 * 72];

  const int gid = blockIdx.x;
  int b, h, qb, kb_begin, kb_end, slot = 0;
  bool do_g = false;
  if (gid < 1184) {
    int bh = gid / 74, rem = gid % 74;
    b = bh >> 2; h = 8 + (bh & 3);
    int part;
    if (rem < 9)       { qb = rem; part = 0; }
    else if (rem < 27) { int z = rem - 9;  qb = 9 + (z >> 1);  part = z & 1; }
    else if (rem < 54) { int z = rem - 27; int q3 = z / 3; qb = 18 + q3; part = z - 3 * q3; }
    else               { int z = rem - 54; qb = 27 + (z >> 2); part = z & 3; }
    kb_begin = part * 9;
    kb_end = min(part * 9 + 8, qb);
    do_g = (part == 0);
    slot = ((b * 4 + (h - 8)) * 32 + qb) * 4 + part;
  } else {
    int lid = gid - 1184;
    int bh = lid >> 5; b = bh >> 3; h = bh & 7; qb = lid & 31;
    kb_begin = (qb > 4) ? qb - 4 : 0; kb_end = qb;
  }
  const int qb0 = qb * 64;
  const bool is_local = (h < 8);
  const int tid = threadIdx.x, lane = tid & 63, wave = tid >> 6;
  const int ln = lane & 15, quad = lane >> 4;
  const int bh48 = b * NH + h;
  const int bhg = (b << 2) | (h & 3);

  const size_t qoff = (size_t)(b * SQ + qb0 + wave * 16 + ln) * 2304 + h * 64;
  bf16x8 qA0 = *(const bf16x8*)&QKV[qoff + quad * 8];
  bf16x8 qA1 = *(const bf16x8*)&QKV[qoff + 32 + quad * 8];

  bf16x8 onesF;
#pragma unroll
  for (int z = 0; z < 8; ++z) onesF[z] = (__bf16)1.0f;

  f32x4 o[4];
  f32x4 ls = (f32x4){0.f, 0.f, 0.f, 0.f};
#pragma unroll
  for (int dt = 0; dt < 4; ++dt) o[dt] = (f32x4){0.f, 0.f, 0.f, 0.f};

  const int nc = kb_end - kb_begin + 1;
  const int ntiles = nc + (do_g ? 4 : 0);
  const int irow = qb0 + wave * 16 + quad * 4;  // + rg
  const int iw = qb0 + wave * 16;
  const int sr = tid >> 3, sch = tid & 7;
  const int row0 = sr, row1 = 32 + sr;

  // Named prefetch registers (NOT arrays, NOT via lambda: those go to scratch
  // -> 273MB of spill traffic in R7).
  uint4 kpre0, kpre1, vpre0, vpre1;
  {
    if (0 < nc) {
      const int ks = kb_begin * 64;
      kpre0 = *(const uint4*)&QKV[(size_t)(b * SQ + ks + row0) * 2304 + 768 + h * 64 + sch * 8];
      kpre1 = *(const uint4*)&QKV[(size_t)(b * SQ + ks + row1) * 2304 + 768 + h * 64 + sch * 8];
      vpre0 = *(const uint4*)&Vtb[(size_t)bh48 * 131072 + (size_t)row0 * 2048 + ks + sch * 8];
      vpre1 = *(const uint4*)&Vtb[(size_t)bh48 * 131072 + (size_t)row1 * 2048 + ks + sch * 8];
    } else {
      kpre0 = *(const uint4*)&Kg[((size_t)bhg * 256 + row0) * 64 + sch * 8];
      kpre1 = *(const uint4*)&Kg[((size_t)bhg * 256 + row1) * 64 + sch * 8];
      vpre0 = *(const uint4*)&VgT[((size_t)bhg * 64 + row0) * 256 + sch * 8];
      vpre1 = *(const uint4*)&VgT[((size_t)bhg * 64 + row1) * 256 + sch * 8];
    }
  }

  for (int t = 0; t < ntiles; ++t) {
    const bool gph = (t >= nc);
    const int kstart = gph ? 0 : (kb_begin + t) * 64;
    const int kg0 = gph ? (t - nc) * 64 : 0;
    __syncthreads();  // prev iter's P/Vs reads done before restage
    *(uint4*)&Ks[row0 * 72 + sch * 8] = kpre0;
    *(uint4*)&Ks[row1 * 72 + sch * 8] = kpre1;
    *(uint4*)&Vs[row0 * 72 + sch * 8] = vpre0;
    *(uint4*)&Vs[row1 * 72 + sch * 8] = vpre1;
    __syncthreads();

    // prefetch tile t+1 into the (now consumed) named registers
    {
      const int t2 = t + 1;
      if (t2 < nc) {
        const int ks2 = (kb_begin + t2) * 64;
        kpre0 = *(const uint4*)&QKV[(size_t)(b * SQ + ks2 + row0) * 2304 + 768 + h * 64 + sch * 8];
        kpre1 = *(const uint4*)&QKV[(size_t)(b * SQ + ks2 + row1) * 2304 + 768 + h * 64 + sch * 8];
        vpre0 = *(const uint4*)&Vtb[(size_t)bh48 * 131072 + (size_t)row0 * 2048 + ks2 + sch * 8];
        vpre1 = *(const uint4*)&Vtb[(size_t)bh48 * 131072 + (size_t)row1 * 2048 + ks2 + sch * 8];
      } else if (t2 < ntiles) {
        const int kg2 = (t2 - nc) * 64;
        kpre0 = *(const uint4*)&Kg[((size_t)bhg * 256 + kg2 + row0) * 64 + sch * 8];
        kpre1 = *(const uint4*)&Kg[((size_t)bhg * 256 + kg2 + row1) * 64 + sch * 8];
        vpre0 = *(const uint4*)&VgT[((size_t)bhg * 64 + row0) * 256 + kg2 + sch * 8];
        vpre1 = *(const uint4*)&VgT[((size_t)bhg * 64 + row1) * 256 + kg2 + sch * 8];
      }
    }

    float sc[4][4];
    const bool full = !gph && (kstart + 63 <= iw) && (!is_local || kstart >= iw - 241);
#pragma unroll
    for (int nt = 0; nt < 4; ++nt) {
      bf16x8 kF0 = *(const bf16x8*)&Ks[(nt * 16 + ln) * 72 + quad * 8];
      bf16x8 kF1 = *(const bf16x8*)&Ks[(nt * 16 + ln) * 72 + 32 + quad * 8];
      f32x4 c = (f32x4){0.f, 0.f, 0.f, 0.f};
      c = __builtin_amdgcn_mfma_f32_16x16x32_bf16(qA0, kF0, c, 0, 0, 0);
      c = __builtin_amdgcn_mfma_f32_16x16x32_bf16(qA1, kF1, c, 0, 0, 0);
      if (full) {
#pragma unroll
        for (int rg = 0; rg < 4; ++rg) sc[nt][rg] = c[rg] * 0.125f - 8.f;
      } else if (!gph) {
        int j = kstart + nt * 16 + ln;
#pragma unroll
        for (int rg = 0; rg < 4; ++rg) {
          int i = irow + rg;
          bool ok = is_local ? (j >= i - 256 && j <= i) : (j <= i);
          sc[nt][rg] = ok ? (c[rg] * 0.125f - 8.f) : -1e9f;
        }
      } else {
        int jg = gidx[kg0 + nt * 16 + ln];
#pragma unroll
        for (int rg = 0; rg < 4; ++rg) {
          bool ok = jg > (irow + rg);
          sc[nt][rg] = ok ? (c[rg] * 0.125f - 8.f) : -1e9f;
        }
      }
    }
    __syncthreads();  // all waves done reading Ks -> reuse as P

    __bf16* P = (__bf16*)Ks;
#pragma unroll
    for (int rg = 0; rg < 4; ++rg) {
      int prow = (wave * 16 + quad * 4 + rg) * 72;
#pragma unroll
      for (int nt = 0; nt < 4; ++nt)
        P[prow + nt * 16 + ln] = (__bf16)__expf(sc[nt][rg]);
    }
    // same-wave LDS RAW (DS pipe in-order per wave) — no barrier needed
    bf16x8 pF0 = *(const bf16x8*)&Ks[(wave * 16 + ln) * 72 + quad * 8];
    bf16x8 pF1 = *(const bf16x8*)&Ks[(wave * 16 + ln) * 72 + 32 + quad * 8];
    ls = __builtin_amdgcn_mfma_f32_16x16x32_bf16(pF0, onesF, ls, 0, 0, 0);
    ls = __builtin_amdgcn_mfma_f32_16x16x32_bf16(pF1, onesF, ls, 0, 0, 0);
#pragma unroll
    for (int dt = 0; dt < 4; ++dt) {
      bf16x8 vF0 = *(const bf16x8*)&Vs[(dt * 16 + ln) * 72 + quad * 8];
      bf16x8 vF1 = *(const bf16x8*)&Vs[(dt * 16 + ln) * 72 + 32 + quad * 8];
      o[dt] = __builtin_amdgcn_mfma_f32_16x16x32_bf16(pF0, vF0, o[dt], 0, 0, 0);
      o[dt] = __builtin_amdgcn_mfma_f32_16x16x32_bf16(pF1, vF1, o[dt], 0, 0, 0);
    }
  }

  if (gid >= 1184) {  // local: direct write
#pragma unroll
    for (int dt = 0; dt < 4; ++dt)
#pragma unroll
      for (int rg = 0; rg < 4; ++rg) {
        int row = b * SQ + qb0 + wave * 16 + quad * 4 + rg;
        int e = h * 64 + dt * 16 + ln;
        AOut[(size_t)row * 768 + e] = bfbits(o[dt][rg] / ls[rg]);
      }
  } else {  // global: partials
#pragma unroll
    for (int dt = 0; dt < 4; ++dt)
#pragma unroll
      for (int rg = 0; rg < 4; ++rg) {
        int row = wave * 16 + quad * 4 + rg;
        Opart[(size_t)slot * 4096 + row * 64 + dt * 16 + ln] = bfbits(o[dt][rg]);
      }
    if (ln == 0) {
#pragma unroll
      for (int rg = 0; rg < 4; ++rg)
        Lpart[(size_t)slot * 64 + wave * 16 + quad * 4 + rg] = ls[rg];
    }
  }
}

// ---------------- combine split-K partials (global heads) ----------------
__global__ __launch_bounds__(256) void combine_parts(
    const unsigned short* __restrict__ Opart, const float* __restrict__ Lpart,
    unsigned short* __restrict__ AOut) {
  const int bid = blockIdx.x;        // 512 = 16 bh * 32 qb
  const int bh = bid >> 5, qb = bid & 31;
  const int b = bh >> 2, h = 8 + (bh & 3);
  const int np = qb / 9 + 1;
  const int t = threadIdx.x, r = t >> 2, c0 = (t & 3) * 16;
  const int slot0 = (bh * 32 + qb) * 4;
  float acc[16];
#pragma unroll
  for (int z = 0; z < 16; ++z) acc[z] = 0.f;
  float l = 0.f;
  for (int p = 0; p < np; ++p) {
    const unsigned short* src = &Opart[(size_t)(slot0 + p) * 4096 + r * 64 + c0];
    bf16x8 v0 = *(const bf16x8*)&src[0];
    bf16x8 v1 = *(const bf16x8*)&src[8];
#pragma unroll
    for (int z = 0; z < 8; ++z) { acc[z] += (float)v0[z]; acc[8 + z] += (float)v1[z]; }
    l += Lpart[(size_t)(slot0 + p) * 64 + r];
  }
  float inv = 1.f / l;
  unsigned short pk[16];
#pragma unroll
  for (int z = 0; z < 16; ++z) pk[z] = bfbits(acc[z] * inv);
  size_t dst = (size_t)(b * SQ + qb * 64 + r) * 768 + h * 64 + c0;
  *(uint4*)&AOut[dst]     = *(uint4*)&pk[0];
  *(uint4*)&AOut[dst + 8] = *(uint4*)&pk[8];
}

// ---------------- launch ----------------
extern "C" void kernel_launch(void* const* d_in, const int* in_sizes, int n_in,
                              void* d_out, int out_size, void* d_ws, size_t ws_size,
                              hipStream_t stream) {
  const float* x      = (const float*)d_in[0];
  const float* w_attn = (const float*)d_in[1];
  const float* b_attn = (const float*)d_in[2];
  const float* w_proj = (const float*)d_in[3];
  const float* b_proj = (const float*)d_in[4];
  float* out = (float*)d_out;

  char* ws = (char*)d_ws;
  size_t off = 0;
  auto alloc = [&](size_t bytes) {
    void* p = ws + off;
    off += (bytes + 255) & ~(size_t)255;
    return p;
  };
  unsigned short* xb     = (unsigned short*)alloc((size_t)8192 * 768 * 2);   // reused as attn buf
  unsigned short* wattnT = (unsigned short*)alloc((size_t)2304 * 768 * 2);
  unsigned short* wprojT = (unsigned short*)alloc((size_t)768 * 768 * 2);
  unsigned short* qkvb   = (unsigned short*)alloc((size_t)8192 * 2304 * 2);
  unsigned short* Vtb    = (unsigned short*)alloc((size_t)48 * 64 * 2048 * 2);
  unsigned short* Kgb    = (unsigned short*)alloc((size_t)16 * 256 * 64 * 2);
  unsigned short* VgTb   = (unsigned short*)alloc((size_t)16 * 64 * 256 * 2);
  int* gidxb             = (int*)alloc((size_t)256 * 4);
  unsigned short* Opartb = (unsigned short*)alloc((size_t)2048 * 4096 * 2);
  float* Lpartb          = (float*)alloc((size_t)2048 * 64 * 4);
  unsigned short* attnb  = xb;  // xb dead after qkv_gemm

  prep<<<dim3(512 + 72 * 24 + 24 * 24), dim3(256), 0, stream>>>(
      x, xb, w_attn, wattnT, w_proj, wprojT);
  qkv_gemm<<<dim3(18, 64), dim3(256), 0, stream>>>(xb, wattnT, b_attn, qkvb);
  vprep<<<dim3(1536 + 128), dim3(256), 0, stream>>>(qkvb, Vtb, Kgb, VgTb, gidxb);
  attn_kernel<<<dim3(2208), dim3(256), 0, stream>>>(qkvb, Vtb, Kgb, VgTb, gidxb,
                                                    attnb, Opartb, Lpartb);
  combine_parts<<<dim3(512), dim3(256), 0, stream>>>(Opartb, Lpartb, attnb);
  proj_gemm<<<dim3(6, 64), dim3(256), 0, stream>>>(attnb, wprojT, b_proj, out);
}

// Round 9
// 226.401 us; speedup vs baseline: 1.2139x; 1.0754x over previous
//
#include <hip/hip_runtime.h>
#include <stdint.h>

// SparseAttention MI355X bf16-MFMA pipeline. Output f32.
// QKV row-major [B*S][2304] bf16; V^T [B*H][64][2048] bf16 (vprep).
// Attention: CONSTANT-SHIFT softmax (p=exp(s-8), scores |s|<~3) -> partials
// over key-chunks are pure sums -> split-K + combine pass.
// R9: register-prefetch abandoned (compiler spills cross-barrier values:
// R7/R8 showed +40MB scratch traffic, VGPR stuck at 40). Instead: UNIFORM
// fine-grained split-K — every global part <=5 causal tiles, gcol tiles get
// their own part; grid 3440 (13.4 blocks/CU), no tail.
// MFMA 16x16x32 bf16 layouts (HW-verified): A[m=lane&15][k=quad*8+j],
// B[k=quad*8+j][n=lane&15], C/D col=lane&15 row=quad*4+reg.

#define NH 12
#define SQ 2048

typedef __bf16 bf16x8 __attribute__((ext_vector_type(8)));
typedef float f32x4 __attribute__((ext_vector_type(4)));

#define GLOAD_LDS16(g, l)                                                      \
  __builtin_amdgcn_global_load_lds(                                            \
      (__attribute__((address_space(1))) void*)(g),                            \
      (__attribute__((address_space(3))) void*)(l), 16, 0, 0)

__device__ __forceinline__ unsigned short bfbits(float f) {
  __bf16 h = (__bf16)f;
  return *(unsigned short*)&h;
}

// ---------------- prep: x->bf16 + both weight transposes (1 kernel) --------
__global__ __launch_bounds__(256) void prep(
    const float* __restrict__ x, unsigned short* __restrict__ xb,
    const float* __restrict__ w_attn, unsigned short* __restrict__ wattnT,
    const float* __restrict__ w_proj, unsigned short* __restrict__ wprojT) {
  const int bid = blockIdx.x, t = threadIdx.x;
  if (bid < 512) {                 // convert x: 8192*768 floats
    const int n4 = 8192 * 768 / 4;
    for (int i = bid * 256 + t; i < n4; i += 512 * 256) {
      float4 v = ((const float4*)x)[i];
      ((ushort4*)xb)[i] = make_ushort4(bfbits(v.x), bfbits(v.y), bfbits(v.z), bfbits(v.w));
    }
    return;
  }
  __shared__ float tile[32][33];
  const float* in; unsigned short* out; int K, N, tl;
  if (bid < 512 + 72 * 24) { in = w_attn; out = wattnT; K = 768; N = 2304; tl = bid - 512; }
  else                     { in = w_proj; out = wprojT; K = 768; N = 768;  tl = bid - 512 - 72 * 24; }
  const int tpr = N / 32;
  const int n0 = (tl % tpr) * 32, k0 = (tl / tpr) * 32;
  const int tx = t & 31, ty = t >> 5;
  for (int r = ty; r < 32; r += 8) tile[r][tx] = in[(size_t)(k0 + r) * N + n0 + tx];
  __syncthreads();
  for (int r = ty; r < 32; r += 8) out[(size_t)(n0 + r) * K + k0 + tx] = bfbits(tile[tx][r]);
}

// ---------------- vprep: V transpose + gcol gather (1 kernel) ----------------
__global__ __launch_bounds__(256) void vprep(const unsigned short* __restrict__ QKV,
                                             unsigned short* __restrict__ Vtb,
                                             unsigned short* __restrict__ Kg,
                                             unsigned short* __restrict__ VgT,
                                             int* __restrict__ gidx) {
  const int id = blockIdx.x, t = threadIdx.x;
  if (id < 1536) {                 // vtrans
    const int bh = id >> 5, b = bh / NH, h = bh % NH;
    const int s0 = (id & 31) * 64;
    __shared__ unsigned short T[64][72];
    const int r = t >> 2, c0 = (t & 3) * 16;
    const size_t src = (size_t)(b * SQ + s0 + r) * 2304 + 1536 + h * 64 + c0;
    *(uint4*)&T[r][c0]     = *(const uint4*)&QKV[src];
    *(uint4*)&T[r][c0 + 8] = *(const uint4*)&QKV[src + 8];
    __syncthreads();
    unsigned short pk[16];
#pragma unroll
    for (int z = 0; z < 16; ++z) pk[z] = T[c0 + z][r];
    size_t dst = (size_t)bh * 131072 + (size_t)r * 2048 + s0 + c0;
    *(uint4*)&Vtb[dst]     = *(uint4*)&pk[0];
    *(uint4*)&Vtb[dst + 8] = *(uint4*)&pk[8];
    return;
  }
  const int g = id - 1536;         // gather: 16 bh * 8 chunks
  const int bh = g >> 3, y = g & 7;
  const int b = bh >> 2, h = 8 + (bh & 3);
  if (g == 0) {
    int c = t;
    gidx[c] = (c < 203) ? (int)((double)c * (2047.0 / 203.0)) : ((c == 203) ? 2047 : -1);
  }
  {  // Kg rows from qkvb K-section
    int c = t, ch = y;
    int col = (c < 203) ? (int)((double)c * (2047.0 / 203.0)) : ((c == 203) ? 2047 : -1);
    uint4 v = {0u, 0u, 0u, 0u};
    if (col >= 0) v = *(const uint4*)&QKV[(size_t)(b * SQ + col) * 2304 + 768 + h * 64 + ch * 8];
    *(uint4*)&Kg[((size_t)bh * 256 + c) * 64 + ch * 8] = v;
  }
  {  // VgT directly from qkvb V-section (transpose gather)
    int d = t >> 2;
    int cb = (t & 3) * 64 + y * 8;
    for (int cc = 0; cc < 8; ++cc) {
      int c = cb + cc;
      int col = (c < 203) ? (int)((double)c * (2047.0 / 203.0)) : ((c == 203) ? 2047 : -1);
      unsigned short v = 0;
      if (col >= 0) v = QKV[(size_t)(b * SQ + col) * 2304 + 1536 + h * 64 + d];
      VgT[((size_t)bh * 64 + d) * 256 + c] = v;
    }
  }
}

// ---------------- GEMM mainloop (BM=BN=128, BK=32, async LDS DMA) ----------
__device__ __forceinline__ void gemm_mainloop(
    const unsigned short* __restrict__ A, const unsigned short* __restrict__ BT,
    int m0, int n0, int tid,
    unsigned short* As, unsigned short* Bs,   // 128 x 32 bf16, UNPADDED
    f32x4 acc[4][4]) {
  const int lane = tid & 63, wave = tid >> 6;
  const int wm = wave >> 1, wn = wave & 1;
  const int ln = lane & 15, quad = lane >> 4;
  const int arow = wave * 16 + (lane >> 2);
  const int acol = (lane & 3) * 8;

#pragma unroll
  for (int mi = 0; mi < 4; ++mi)
#pragma unroll
    for (int ni = 0; ni < 4; ++ni) acc[mi][ni] = (f32x4){0.f, 0.f, 0.f, 0.f};

  for (int kt = 0; kt < 24; ++kt) {
    const int k0 = kt * 32;
    __syncthreads();
#pragma unroll
    for (int p = 0; p < 2; ++p) {
      GLOAD_LDS16(A  + (size_t)(m0 + p * 64 + arow) * 768 + k0 + acol,
                  &As[(p * 64 + wave * 16) * 32]);
      GLOAD_LDS16(BT + (size_t)(n0 + p * 64 + arow) * 768 + k0 + acol,
                  &Bs[(p * 64 + wave * 16) * 32]);
    }
    __syncthreads();
    bf16x8 aF[4], bF[4];
#pragma unroll
    for (int mi = 0; mi < 4; ++mi) aF[mi] = *(const bf16x8*)&As[(wm * 64 + mi * 16 + ln) * 32 + quad * 8];
#pragma unroll
    for (int ni = 0; ni < 4; ++ni) bF[ni] = *(const bf16x8*)&Bs[(wn * 64 + ni * 16 + ln) * 32 + quad * 8];
#pragma unroll
    for (int mi = 0; mi < 4; ++mi)
#pragma unroll
      for (int ni = 0; ni < 4; ++ni)
        acc[mi][ni] = __builtin_amdgcn_mfma_f32_16x16x32_bf16(aF[mi], bF[ni], acc[mi][ni], 0, 0, 0);
  }
}

// ---------------- QKV GEMM: row-major bf16 out ----------------
__global__ __launch_bounds__(256) void qkv_gemm(
    const unsigned short* __restrict__ Xb, const unsigned short* __restrict__ WT,
    const float* __restrict__ bias, unsigned short* __restrict__ Out) {
  __shared__ __attribute__((aligned(16))) unsigned short As[128 * 32];
  __shared__ __attribute__((aligned(16))) unsigned short Bs[128 * 32];
  f32x4 acc[4][4];
  const int m0 = blockIdx.y * 128, n0 = blockIdx.x * 128;
  const int tid = threadIdx.x;
  gemm_mainloop(Xb, WT, m0, n0, tid, As, Bs, acc);
  const int lane = tid & 63, wave = tid >> 6;
  const int wm = wave >> 1, wn = wave & 1, ln = lane & 15, quad = lane >> 4;
#pragma unroll
  for (int mi = 0; mi < 4; ++mi)
#pragma unroll
    for (int ni = 0; ni < 4; ++ni) {
      int n = n0 + wn * 64 + ni * 16 + ln;
      float bs = bias[n];
#pragma unroll
      for (int rg = 0; rg < 4; ++rg) {
        int m = m0 + wm * 64 + mi * 16 + quad * 4 + rg;
        Out[(size_t)m * 2304 + n] = bfbits(acc[mi][ni][rg] + bs);
      }
    }
}

// ---------------- Proj GEMM: fp32 out ----------------
__global__ __launch_bounds__(256) void proj_gemm(
    const unsigned short* __restrict__ Ab, const unsigned short* __restrict__ WT,
    const float* __restrict__ bias, float* __restrict__ Out) {
  __shared__ __attribute__((aligned(16))) unsigned short As[128 * 32];
  __shared__ __attribute__((aligned(16))) unsigned short Bs[128 * 32];
  f32x4 acc[4][4];
  const int m0 = blockIdx.y * 128, n0 = blockIdx.x * 128;
  const int tid = threadIdx.x;
  gemm_mainloop(Ab, WT, m0, n0, tid, As, Bs, acc);
  const int lane = tid & 63, wave = tid >> 6;
  const int wm = wave >> 1, wn = wave & 1, ln = lane & 15, quad = lane >> 4;
#pragma unroll
  for (int mi = 0; mi < 4; ++mi)
#pragma unroll
    for (int ni = 0; ni < 4; ++ni)
#pragma unroll
      for (int rg = 0; rg < 4; ++rg) {
        int m = m0 + wm * 64 + mi * 16 + quad * 4 + rg;
        int n = n0 + wn * 64 + ni * 16 + ln;
        Out[(size_t)m * 768 + n] = acc[mi][ni][rg] + bias[n];
      }
}

// ---------------- Flash attention: uniform fine split-K ----------------
// Grid 3440. gid<2416: global parts (151/bh16): rem<32 -> gcol-only part
// (4 tiles, qb=rem); else causal part of <=5 tiles via triangular decode
// (band w=qb/5 has w+1 parts/qb, cum base 5w(w+1)/2). slot = gid.
// gid>=2416: locals (<=5 tiles), direct write.
__global__ __launch_bounds__(256, 6) void attn_kernel(
    const unsigned short* __restrict__ QKV,   // [8192][2304]
    const unsigned short* __restrict__ Vtb,   // [48][64][2048]
    const unsigned short* __restrict__ Kg, const unsigned short* __restrict__ VgT,
    const int* __restrict__ gidx,
    unsigned short* __restrict__ AOut,        // [8192][768]
    unsigned short* __restrict__ Opart,       // [2416][4096] bf16
    float* __restrict__ Lpart) {              // [2416][64]
  __shared__ __attribute__((aligned(16))) unsigned short Ks[64 * 72];  // also P
  __shared__ __attribute__((aligned(16))) unsigned short Vs[64 * 72];

  const int gid = blockIdx.x;
  int b, h, qb, kb_begin = 0, kb_end = -1;   // empty causal range by default
  bool do_g = false, is_global_part = (gid < 2416);
  if (is_global_part) {
    int bh = gid / 151, rem = gid % 151;
    b = bh >> 2; h = 8 + (bh & 3);
    if (rem < 32) {            // gcol-only part
      qb = rem; do_g = true;
    } else {                   // causal part
      int z = rem - 32;
      int w = 0;
      while (z >= 5 * (w + 1) * (w + 2) / 2) ++w;   // uniform, <=6 iters
      int off = z - 5 * w * (w + 1) / 2;
      int qpd = w + 1;
      qb = 5 * w + off / qpd;
      int p = off % qpd;
      kb_begin = 5 * p;
      kb_end = min(5 * p + 4, qb);
    }
  } else {
    int lid = gid - 2416;
    int bh = lid >> 5; b = bh >> 3; h = bh & 7; qb = lid & 31;
    kb_begin = (qb > 4) ? qb - 4 : 0; kb_end = qb;
  }
  const int qb0 = qb * 64;
  const bool is_local = (h < 8);
  const int tid = threadIdx.x, lane = tid & 63, wave = tid >> 6;
  const int ln = lane & 15, quad = lane >> 4;
  const int bh48 = b * NH + h;
  const int bhg = (b << 2) | (h & 3);

  const size_t qoff = (size_t)(b * SQ + qb0 + wave * 16 + ln) * 2304 + h * 64;
  bf16x8 qA0 = *(const bf16x8*)&QKV[qoff + quad * 8];
  bf16x8 qA1 = *(const bf16x8*)&QKV[qoff + 32 + quad * 8];

  bf16x8 onesF;
#pragma unroll
  for (int z = 0; z < 8; ++z) onesF[z] = (__bf16)1.0f;

  f32x4 o[4];
  f32x4 ls = (f32x4){0.f, 0.f, 0.f, 0.f};
#pragma unroll
  for (int dt = 0; dt < 4; ++dt) o[dt] = (f32x4){0.f, 0.f, 0.f, 0.f};

  const int nc = kb_end - kb_begin + 1;        // 0 for gcol-only parts
  const int ntiles = nc + (do_g ? 4 : 0);
  const int irow = qb0 + wave * 16 + quad * 4;  // + rg
  const int iw = qb0 + wave * 16;
  const int sr = tid >> 3, sch = tid & 7;

  for (int t = 0; t < ntiles; ++t) {
    const bool gph = (t >= nc);
    const int kstart = gph ? 0 : (kb_begin + t) * 64;
    const int kg0 = gph ? (t - nc) * 64 : 0;
    __syncthreads();  // prev iter's P/Vs reads done before restage
    if (!gph) {
#pragma unroll
      for (int p = 0; p < 2; ++p) {
        int row = p * 32 + sr;
        *(uint4*)&Ks[row * 72 + sch * 8] =
            *(const uint4*)&QKV[(size_t)(b * SQ + kstart + row) * 2304 + 768 + h * 64 + sch * 8];
        *(uint4*)&Vs[row * 72 + sch * 8] =
            *(const uint4*)&Vtb[(size_t)bh48 * 131072 + (size_t)row * 2048 + kstart + sch * 8];
      }
    } else {
#pragma unroll
      for (int p = 0; p < 2; ++p) {
        int row = p * 32 + sr;
        *(uint4*)&Ks[row * 72 + sch * 8] =
            *(const uint4*)&Kg[((size_t)bhg * 256 + kg0 + row) * 64 + sch * 8];
        *(uint4*)&Vs[row * 72 + sch * 8] =
            *(const uint4*)&VgT[((size_t)bhg * 64 + row) * 256 + kg0 + sch * 8];
      }
    }
    __syncthreads();

    float sc[4][4];
    const bool full = !gph && (kstart + 63 <= iw) && (!is_local || kstart >= iw - 241);
#pragma unroll
    for (int nt = 0; nt < 4; ++nt) {
      bf16x8 kF0 = *(const bf16x8*)&Ks[(nt * 16 + ln) * 72 + quad * 8];
      bf16x8 kF1 = *(const bf16x8*)&Ks[(nt * 16 + ln) * 72 + 32 + quad * 8];
      f32x4 c = (f32x4){0.f, 0.f, 0.f, 0.f};
      c = __builtin_amdgcn_mfma_f32_16x16x32_bf16(qA0, kF0, c, 0, 0, 0);
      c = __builtin_amdgcn_mfma_f32_16x16x32_bf16(qA1, kF1, c, 0, 0, 0);
      if (full) {
#pragma unroll
        for (int rg = 0; rg < 4; ++rg) sc[nt][rg] = c[rg] * 0.125f - 8.f;
      } else if (!gph) {
        int j = kstart + nt * 16 + ln;
#pragma unroll
        for (int rg = 0; rg < 4; ++rg) {
          int i = irow + rg;
          bool ok = is_local ? (j >= i - 256 && j <= i) : (j <= i);
          sc[nt][rg] = ok ? (c[rg] * 0.125f - 8.f) : -1e9f;
        }
      } else {
        int jg = gidx[kg0 + nt * 16 + ln];
#pragma unroll
        for (int rg = 0; rg < 4; ++rg) {
          bool ok = jg > (irow + rg);
          sc[nt][rg] = ok ? (c[rg] * 0.125f - 8.f) : -1e9f;
        }
      }
    }
    __syncthreads();  // all waves done reading Ks -> reuse as P

    __bf16* P = (__bf16*)Ks;
#pragma unroll
    for (int rg = 0; rg < 4; ++rg) {
      int prow = (wave * 16 + quad * 4 + rg) * 72;
#pragma unroll
      for (int nt = 0; nt < 4; ++nt)
        P[prow + nt * 16 + ln] = (__bf16)__expf(sc[nt][rg]);
    }
    // same-wave LDS RAW (DS pipe in-order per wave) — no barrier needed
    bf16x8 pF0 = *(const bf16x8*)&Ks[(wave * 16 + ln) * 72 + quad * 8];
    bf16x8 pF1 = *(const bf16x8*)&Ks[(wave * 16 + ln) * 72 + 32 + quad * 8];
    ls = __builtin_amdgcn_mfma_f32_16x16x32_bf16(pF0, onesF, ls, 0, 0, 0);
    ls = __builtin_amdgcn_mfma_f32_16x16x32_bf16(pF1, onesF, ls, 0, 0, 0);
#pragma unroll
    for (int dt = 0; dt < 4; ++dt) {
      bf16x8 vF0 = *(const bf16x8*)&Vs[(dt * 16 + ln) * 72 + quad * 8];
      bf16x8 vF1 = *(const bf16x8*)&Vs[(dt * 16 + ln) * 72 + 32 + quad * 8];
      o[dt] = __builtin_amdgcn_mfma_f32_16x16x32_bf16(pF0, vF0, o[dt], 0, 0, 0);
      o[dt] = __builtin_amdgcn_mfma_f32_16x16x32_bf16(pF1, vF1, o[dt], 0, 0, 0);
    }
  }

  if (!is_global_part) {  // local: direct write
#pragma unroll
    for (int dt = 0; dt < 4; ++dt)
#pragma unroll
      for (int rg = 0; rg < 4; ++rg) {
        int row = b * SQ + qb0 + wave * 16 + quad * 4 + rg;
        int e = h * 64 + dt * 16 + ln;
        AOut[(size_t)row * 768 + e] = bfbits(o[dt][rg] / ls[rg]);
      }
  } else {  // global: partials, slot == gid
#pragma unroll
    for (int dt = 0; dt < 4; ++dt)
#pragma unroll
      for (int rg = 0; rg < 4; ++rg) {
        int row = wave * 16 + quad * 4 + rg;
        Opart[(size_t)gid * 4096 + row * 64 + dt * 16 + ln] = bfbits(o[dt][rg]);
      }
    if (ln == 0) {
#pragma unroll
      for (int rg = 0; rg < 4; ++rg)
        Lpart[(size_t)gid * 64 + wave * 16 + quad * 4 + rg] = ls[rg];
    }
  }
}

// ---------------- combine split-K partials (global heads) ----------------
__global__ __launch_bounds__(256) void combine_parts(
    const unsigned short* __restrict__ Opart, const float* __restrict__ Lpart,
    unsigned short* __restrict__ AOut) {
  const int bid = blockIdx.x;        // 512 = 16 bh * 32 qb
  const int bh = bid >> 5, qb = bid & 31;
  const int b = bh >> 2, h = 8 + (bh & 3);
  const int w = qb / 5;              // band; w+1 causal parts
  const int causal0 = bh * 151 + 32 + 5 * w * (w + 1) / 2 + (qb - 5 * w) * (w + 1);
  const int gslot = bh * 151 + qb;   // gcol-only part
  const int t = threadIdx.x, r = t >> 2, c0 = (t & 3) * 16;
  float acc[16];
#pragma unroll
  for (int z = 0; z < 16; ++z) acc[z] = 0.f;
  float l = 0.f;
  for (int p = 0; p <= w + 1; ++p) {            // w+1 causal parts + 1 gcol
    int slot = (p <= w) ? (causal0 + p) : gslot;
    const unsigned short* src = &Opart[(size_t)slot * 4096 + r * 64 + c0];
    bf16x8 v0 = *(const bf16x8*)&src[0];
    bf16x8 v1 = *(const bf16x8*)&src[8];
#pragma unroll
    for (int z = 0; z < 8; ++z) { acc[z] += (float)v0[z]; acc[8 + z] += (float)v1[z]; }
    l += Lpart[(size_t)slot * 64 + r];
  }
  float inv = 1.f / l;
  unsigned short pk[16];
#pragma unroll
  for (int z = 0; z < 16; ++z) pk[z] = bfbits(acc[z] * inv);
  size_t dst = (size_t)(b * SQ + qb * 64 + r) * 768 + h * 64 + c0;
  *(uint4*)&AOut[dst]     = *(uint4*)&pk[0];
  *(uint4*)&AOut[dst + 8] = *(uint4*)&pk[8];
}

// ---------------- launch ----------------
extern "C" void kernel_launch(void* const* d_in, const int* in_sizes, int n_in,
                              void* d_out, int out_size, void* d_ws, size_t ws_size,
                              hipStream_t stream) {
  const float* x      = (const float*)d_in[0];
  const float* w_attn = (const float*)d_in[1];
  const float* b_attn = (const float*)d_in[2];
  const float* w_proj = (const float*)d_in[3];
  const float* b_proj = (const float*)d_in[4];
  float* out = (float*)d_out;

  char* ws = (char*)d_ws;
  size_t off = 0;
  auto alloc = [&](size_t bytes) {
    void* p = ws + off;
    off += (bytes + 255) & ~(size_t)255;
    return p;
  };
  unsigned short* xb     = (unsigned short*)alloc((size_t)8192 * 768 * 2);   // reused as attn buf
  unsigned short* wattnT = (unsigned short*)alloc((size_t)2304 * 768 * 2);
  unsigned short* wprojT = (unsigned short*)alloc((size_t)768 * 768 * 2);
  unsigned short* qkvb   = (unsigned short*)alloc((size_t)8192 * 2304 * 2);
  unsigned short* Vtb    = (unsigned short*)alloc((size_t)48 * 64 * 2048 * 2);
  unsigned short* Kgb    = (unsigned short*)alloc((size_t)16 * 256 * 64 * 2);
  unsigned short* VgTb   = (unsigned short*)alloc((size_t)16 * 64 * 256 * 2);
  int* gidxb             = (int*)alloc((size_t)256 * 4);
  unsigned short* Opartb = (unsigned short*)alloc((size_t)2416 * 4096 * 2);
  float* Lpartb          = (float*)alloc((size_t)2416 * 64 * 4);
  unsigned short* attnb  = xb;  // xb dead after qkv_gemm

  prep<<<dim3(512 + 72 * 24 + 24 * 24), dim3(256), 0, stream>>>(
      x, xb, w_attn, wattnT, w_proj, wprojT);
  qkv_gemm<<<dim3(18, 64), dim3(256), 0, stream>>>(xb, wattnT, b_attn, qkvb);
  vprep<<<dim3(1536 + 128), dim3(256), 0, stream>>>(qkvb, Vtb, Kgb, VgTb, gidxb);
  attn_kernel<<<dim3(3440), dim3(256), 0, stream>>>(qkvb, Vtb, Kgb, VgTb, gidxb,
                                                    attnb, Opartb, Lpartb);
  combine_parts<<<dim3(512), dim3(256), 0, stream>>>(Opartb, Lpartb, attnb);
  proj_gemm<<<dim3(6, 64), dim3(256), 0, stream>>>(attnb, wprojT, b_proj, out);
}

// Round 10
// 224.450 us; speedup vs baseline: 1.2245x; 1.0087x over previous
//
#include <hip/hip_runtime.h>
#include <stdint.h>

// SparseAttention MI355X bf16-MFMA pipeline. Output f32.
// QKV row-major [B*S][2304] bf16; V^T [B*H][64][2048] bf16 (vprep).
// Attention: CONSTANT-SHIFT softmax (p=exp(s-8), scores |s|<~3) -> partials
// over key-chunks are pure sums -> split-K for global heads + combine pass.
// R10: attn = exact R5 structure (best measured: 55us; R6 density, R7/R8
// reg-prefetch (compiler spills cross-barrier regs), R9 uniform-split all
// regressed). GEMMs move to BN=64 tiles: 2x grid concurrency (qkv 2304
// blocks, proj 768), acc 2x4/wave, VGPR ~90 -> more waves/CU.
// MFMA 16x16x32 bf16 layouts (HW-verified): A[m=lane&15][k=quad*8+j],
// B[k=quad*8+j][n=lane&15], C/D col=lane&15 row=quad*4+reg.

#define NH 12
#define SQ 2048

typedef __bf16 bf16x8 __attribute__((ext_vector_type(8)));
typedef float f32x4 __attribute__((ext_vector_type(4)));

#define GLOAD_LDS16(g, l)                                                      \
  __builtin_amdgcn_global_load_lds(                                            \
      (__attribute__((address_space(1))) void*)(g),                            \
      (__attribute__((address_space(3))) void*)(l), 16, 0, 0)

__device__ __forceinline__ unsigned short bfbits(float f) {
  __bf16 h = (__bf16)f;
  return *(unsigned short*)&h;
}

// ---------------- prep: x->bf16 + both weight transposes (1 kernel) --------
__global__ __launch_bounds__(256) void prep(
    const float* __restrict__ x, unsigned short* __restrict__ xb,
    const float* __restrict__ w_attn, unsigned short* __restrict__ wattnT,
    const float* __restrict__ w_proj, unsigned short* __restrict__ wprojT) {
  const int bid = blockIdx.x, t = threadIdx.x;
  if (bid < 512) {                 // convert x: 8192*768 floats
    const int n4 = 8192 * 768 / 4;
    for (int i = bid * 256 + t; i < n4; i += 512 * 256) {
      float4 v = ((const float4*)x)[i];
      ((ushort4*)xb)[i] = make_ushort4(bfbits(v.x), bfbits(v.y), bfbits(v.z), bfbits(v.w));
    }
    return;
  }
  __shared__ float tile[32][33];
  const float* in; unsigned short* out; int K, N, tl;
  if (bid < 512 + 72 * 24) { in = w_attn; out = wattnT; K = 768; N = 2304; tl = bid - 512; }
  else                     { in = w_proj; out = wprojT; K = 768; N = 768;  tl = bid - 512 - 72 * 24; }
  const int tpr = N / 32;
  const int n0 = (tl % tpr) * 32, k0 = (tl / tpr) * 32;
  const int tx = t & 31, ty = t >> 5;
  for (int r = ty; r < 32; r += 8) tile[r][tx] = in[(size_t)(k0 + r) * N + n0 + tx];
  __syncthreads();
  for (int r = ty; r < 32; r += 8) out[(size_t)(n0 + r) * K + k0 + tx] = bfbits(tile[tx][r]);
}

// ---------------- vprep: V transpose + gcol gather (1 kernel) ----------------
__global__ __launch_bounds__(256) void vprep(const unsigned short* __restrict__ QKV,
                                             unsigned short* __restrict__ Vtb,
                                             unsigned short* __restrict__ Kg,
                                             unsigned short* __restrict__ VgT,
                                             int* __restrict__ gidx) {
  const int id = blockIdx.x, t = threadIdx.x;
  if (id < 1536) {                 // vtrans
    const int bh = id >> 5, b = bh / NH, h = bh % NH;
    const int s0 = (id & 31) * 64;
    __shared__ unsigned short T[64][72];
    const int r = t >> 2, c0 = (t & 3) * 16;
    const size_t src = (size_t)(b * SQ + s0 + r) * 2304 + 1536 + h * 64 + c0;
    *(uint4*)&T[r][c0]     = *(const uint4*)&QKV[src];
    *(uint4*)&T[r][c0 + 8] = *(const uint4*)&QKV[src + 8];
    __syncthreads();
    unsigned short pk[16];
#pragma unroll
    for (int z = 0; z < 16; ++z) pk[z] = T[c0 + z][r];
    size_t dst = (size_t)bh * 131072 + (size_t)r * 2048 + s0 + c0;
    *(uint4*)&Vtb[dst]     = *(uint4*)&pk[0];
    *(uint4*)&Vtb[dst + 8] = *(uint4*)&pk[8];
    return;
  }
  const int g = id - 1536;         // gather: 16 bh * 8 chunks
  const int bh = g >> 3, y = g & 7;
  const int b = bh >> 2, h = 8 + (bh & 3);
  if (g == 0) {
    int c = t;
    gidx[c] = (c < 203) ? (int)((double)c * (2047.0 / 203.0)) : ((c == 203) ? 2047 : -1);
  }
  {  // Kg rows from qkvb K-section
    int c = t, ch = y;
    int col = (c < 203) ? (int)((double)c * (2047.0 / 203.0)) : ((c == 203) ? 2047 : -1);
    uint4 v = {0u, 0u, 0u, 0u};
    if (col >= 0) v = *(const uint4*)&QKV[(size_t)(b * SQ + col) * 2304 + 768 + h * 64 + ch * 8];
    *(uint4*)&Kg[((size_t)bh * 256 + c) * 64 + ch * 8] = v;
  }
  {  // VgT directly from qkvb V-section (transpose gather)
    int d = t >> 2;
    int cb = (t & 3) * 64 + y * 8;
    for (int cc = 0; cc < 8; ++cc) {
      int c = cb + cc;
      int col = (c < 203) ? (int)((double)c * (2047.0 / 203.0)) : ((c == 203) ? 2047 : -1);
      unsigned short v = 0;
      if (col >= 0) v = QKV[(size_t)(b * SQ + col) * 2304 + 1536 + h * 64 + d];
      VgT[((size_t)bh * 64 + d) * 256 + c] = v;
    }
  }
}

// ---------- GEMM mainloop (BM=128, BN=64, BK=32, async LDS DMA) ------------
// Wave w owns M rows [w*32, w*32+32) x all 64 N cols: acc[2][4].
__device__ __forceinline__ void gemm_mainloop64(
    const unsigned short* __restrict__ A, const unsigned short* __restrict__ BT,
    int m0, int n0, int tid,
    unsigned short* As, unsigned short* Bs,   // As 128x32, Bs 64x32, UNPADDED
    f32x4 acc[2][4]) {
  const int lane = tid & 63, wave = tid >> 6;
  const int ln = lane & 15, quad = lane >> 4;
  const int arow = wave * 16 + (lane >> 2);  // staging row (+p*64 for A)
  const int acol = (lane & 3) * 8;

#pragma unroll
  for (int mi = 0; mi < 2; ++mi)
#pragma unroll
    for (int ni = 0; ni < 4; ++ni) acc[mi][ni] = (f32x4){0.f, 0.f, 0.f, 0.f};

  for (int kt = 0; kt < 24; ++kt) {
    const int k0 = kt * 32;
    __syncthreads();
#pragma unroll
    for (int p = 0; p < 2; ++p)
      GLOAD_LDS16(A + (size_t)(m0 + p * 64 + arow) * 768 + k0 + acol,
                  &As[(p * 64 + wave * 16) * 32]);
    GLOAD_LDS16(BT + (size_t)(n0 + arow) * 768 + k0 + acol,
                &Bs[(wave * 16) * 32]);
    __syncthreads();
    bf16x8 aF[2], bF[4];
#pragma unroll
    for (int mi = 0; mi < 2; ++mi)
      aF[mi] = *(const bf16x8*)&As[(wave * 32 + mi * 16 + ln) * 32 + quad * 8];
#pragma unroll
    for (int ni = 0; ni < 4; ++ni)
      bF[ni] = *(const bf16x8*)&Bs[(ni * 16 + ln) * 32 + quad * 8];
#pragma unroll
    for (int mi = 0; mi < 2; ++mi)
#pragma unroll
      for (int ni = 0; ni < 4; ++ni)
        acc[mi][ni] = __builtin_amdgcn_mfma_f32_16x16x32_bf16(aF[mi], bF[ni], acc[mi][ni], 0, 0, 0);
  }
}

// ---------------- QKV GEMM: row-major bf16 out ----------------
__global__ __launch_bounds__(256) void qkv_gemm(
    const unsigned short* __restrict__ Xb, const unsigned short* __restrict__ WT,
    const float* __restrict__ bias, unsigned short* __restrict__ Out) {
  __shared__ __attribute__((aligned(16))) unsigned short As[128 * 32];
  __shared__ __attribute__((aligned(16))) unsigned short Bs[64 * 32];
  f32x4 acc[2][4];
  const int m0 = blockIdx.y * 128, n0 = blockIdx.x * 64;
  const int tid = threadIdx.x;
  gemm_mainloop64(Xb, WT, m0, n0, tid, As, Bs, acc);
  const int lane = tid & 63, wave = tid >> 6;
  const int ln = lane & 15, quad = lane >> 4;
#pragma unroll
  for (int mi = 0; mi < 2; ++mi)
#pragma unroll
    for (int ni = 0; ni < 4; ++ni) {
      int n = n0 + ni * 16 + ln;
      float bs = bias[n];
#pragma unroll
      for (int rg = 0; rg < 4; ++rg) {
        int m = m0 + wave * 32 + mi * 16 + quad * 4 + rg;
        Out[(size_t)m * 2304 + n] = bfbits(acc[mi][ni][rg] + bs);
      }
    }
}

// ---------------- Proj GEMM: fp32 out ----------------
__global__ __launch_bounds__(256) void proj_gemm(
    const unsigned short* __restrict__ Ab, const unsigned short* __restrict__ WT,
    const float* __restrict__ bias, float* __restrict__ Out) {
  __shared__ __attribute__((aligned(16))) unsigned short As[128 * 32];
  __shared__ __attribute__((aligned(16))) unsigned short Bs[64 * 32];
  f32x4 acc[2][4];
  const int m0 = blockIdx.y * 128, n0 = blockIdx.x * 64;
  const int tid = threadIdx.x;
  gemm_mainloop64(Ab, WT, m0, n0, tid, As, Bs, acc);
  const int lane = tid & 63, wave = tid >> 6;
  const int ln = lane & 15, quad = lane >> 4;
#pragma unroll
  for (int mi = 0; mi < 2; ++mi)
#pragma unroll
    for (int ni = 0; ni < 4; ++ni) {
      int n = n0 + ni * 16 + ln;
      float bs = bias[n];
#pragma unroll
      for (int rg = 0; rg < 4; ++rg) {
        int m = m0 + wave * 32 + mi * 16 + quad * 4 + rg;
        Out[(size_t)m * 768 + n] = acc[mi][ni][rg] + bs;
      }
    }
}

// ---------------- Flash attention (exact R5 structure, best measured) ------
// Grid 2208: [0,1184) global-head parts (<=13 tiles), [1184,2208) local (<=5).
// Global parts: causal kb in [9p, min(9p+8,qb)]; part 0 also does 4 gcol
// tiles. Partials (bf16 O, f32 l) -> combine kernel. Locals + single-part
// globals (qb<=8) write direct.
__global__ __launch_bounds__(256, 6) void attn_kernel(
    const unsigned short* __restrict__ QKV,   // [8192][2304]
    const unsigned short* __restrict__ Vtb,   // [48][64][2048]
    const unsigned short* __restrict__ Kg, const unsigned short* __restrict__ VgT,
    const int* __restrict__ gidx,
    unsigned short* __restrict__ AOut,        // [8192][768]
    unsigned short* __restrict__ Opart,       // [2048][4096] bf16
    float* __restrict__ Lpart) {              // [2048][64]
  __shared__ __attribute__((aligned(16))) unsigned short Ks[64 * 72];  // also P
  __shared__ __attribute__((aligned(16))) unsigned short Vs[64 * 72];

  const int gid = blockIdx.x;
  int b, h, qb, kb_begin, kb_end, slot = 0;
  bool do_g = false, multi = false;
  if (gid < 1184) {
    int bh = gid / 74, rem = gid % 74;
    b = bh >> 2; h = 8 + (bh & 3);
    int part;
    if (rem < 9)       { qb = rem; part = 0; }
    else if (rem < 27) { int z = rem - 9;  qb = 9 + (z >> 1);  part = z & 1; }
    else if (rem < 54) { int z = rem - 27; int q3 = z / 3; qb = 18 + q3; part = z - 3 * q3; }
    else               { int z = rem - 54; qb = 27 + (z >> 2); part = z & 3; }
    kb_begin = part * 9;
    kb_end = min(part * 9 + 8, qb);
    do_g = (part == 0);
    multi = (qb >= 9);
    slot = (bh * 32 + qb) * 4 + part;
  } else {
    int lid = gid - 1184;
    int bh = lid >> 5; b = bh >> 3; h = bh & 7; qb = lid & 31;
    kb_begin = (qb > 4) ? qb - 4 : 0; kb_end = qb;
  }
  const int qb0 = qb * 64;
  const bool is_local = (h < 8);
  const int tid = threadIdx.x, lane = tid & 63, wave = tid >> 6;
  const int ln = lane & 15, quad = lane >> 4;
  const int bh48 = b * NH + h;
  const int bhg = (b << 2) | (h & 3);

  const size_t qoff = (size_t)(b * SQ + qb0 + wave * 16 + ln) * 2304 + h * 64;
  bf16x8 qA0 = *(const bf16x8*)&QKV[qoff + quad * 8];
  bf16x8 qA1 = *(const bf16x8*)&QKV[qoff + 32 + quad * 8];

  bf16x8 onesF;
#pragma unroll
  for (int z = 0; z < 8; ++z) onesF[z] = (__bf16)1.0f;

  f32x4 o[4];
  f32x4 ls = (f32x4){0.f, 0.f, 0.f, 0.f};
#pragma unroll
  for (int dt = 0; dt < 4; ++dt) o[dt] = (f32x4){0.f, 0.f, 0.f, 0.f};

  const int nc = kb_end - kb_begin + 1;
  const int ntiles = nc + (do_g ? 4 : 0);
  const int irow = qb0 + wave * 16 + quad * 4;  // + rg
  const int iw = qb0 + wave * 16;
  const int sr = tid >> 3, sch = tid & 7;

  for (int t = 0; t < ntiles; ++t) {
    const bool gph = (t >= nc);
    const int kstart = gph ? 0 : (kb_begin + t) * 64;
    const int kg0 = gph ? (t - nc) * 64 : 0;
    __syncthreads();  // prev iter's P/Vs reads done before restage
    if (!gph) {
#pragma unroll
      for (int p = 0; p < 2; ++p) {
        int row = p * 32 + sr;
        *(uint4*)&Ks[row * 72 + sch * 8] =
            *(const uint4*)&QKV[(size_t)(b * SQ + kstart + row) * 2304 + 768 + h * 64 + sch * 8];
        *(uint4*)&Vs[row * 72 + sch * 8] =
            *(const uint4*)&Vtb[(size_t)bh48 * 131072 + (size_t)row * 2048 + kstart + sch * 8];
      }
    } else {
#pragma unroll
      for (int p = 0; p < 2; ++p) {
        int row = p * 32 + sr;
        *(uint4*)&Ks[row * 72 + sch * 8] =
            *(const uint4*)&Kg[((size_t)bhg * 256 + kg0 + row) * 64 + sch * 8];
        *(uint4*)&Vs[row * 72 + sch * 8] =
            *(const uint4*)&VgT[((size_t)bhg * 64 + row) * 256 + kg0 + sch * 8];
      }
    }
    __syncthreads();

    float sc[4][4];
    const bool full = !gph && (kstart + 63 <= iw) && (!is_local || kstart >= iw - 241);
#pragma unroll
    for (int nt = 0; nt < 4; ++nt) {
      bf16x8 kF0 = *(const bf16x8*)&Ks[(nt * 16 + ln) * 72 + quad * 8];
      bf16x8 kF1 = *(const bf16x8*)&Ks[(nt * 16 + ln) * 72 + 32 + quad * 8];
      f32x4 c = (f32x4){0.f, 0.f, 0.f, 0.f};
      c = __builtin_amdgcn_mfma_f32_16x16x32_bf16(qA0, kF0, c, 0, 0, 0);
      c = __builtin_amdgcn_mfma_f32_16x16x32_bf16(qA1, kF1, c, 0, 0, 0);
      if (full) {
#pragma unroll
        for (int rg = 0; rg < 4; ++rg) sc[nt][rg] = c[rg] * 0.125f - 8.f;
      } else if (!gph) {
        int j = kstart + nt * 16 + ln;
#pragma unroll
        for (int rg = 0; rg < 4; ++rg) {
          int i = irow + rg;
          bool ok = is_local ? (j >= i - 256 && j <= i) : (j <= i);
          sc[nt][rg] = ok ? (c[rg] * 0.125f - 8.f) : -1e9f;
        }
      } else {
        int jg = gidx[kg0 + nt * 16 + ln];
#pragma unroll
        for (int rg = 0; rg < 4; ++rg) {
          bool ok = jg > (irow + rg);
          sc[nt][rg] = ok ? (c[rg] * 0.125f - 8.f) : -1e9f;
        }
      }
    }
    __syncthreads();  // all waves done reading Ks -> reuse as P

    __bf16* P = (__bf16*)Ks;
#pragma unroll
    for (int rg = 0; rg < 4; ++rg) {
      int prow = (wave * 16 + quad * 4 + rg) * 72;
#pragma unroll
      for (int nt = 0; nt < 4; ++nt)
        P[prow + nt * 16 + ln] = (__bf16)__expf(sc[nt][rg]);
    }
    // same-wave LDS RAW (DS pipe in-order per wave) — no barrier needed
    bf16x8 pF0 = *(const bf16x8*)&Ks[(wave * 16 + ln) * 72 + quad * 8];
    bf16x8 pF1 = *(const bf16x8*)&Ks[(wave * 16 + ln) * 72 + 32 + quad * 8];
    ls = __builtin_amdgcn_mfma_f32_16x16x32_bf16(pF0, onesF, ls, 0, 0, 0);
    ls = __builtin_amdgcn_mfma_f32_16x16x32_bf16(pF1, onesF, ls, 0, 0, 0);
#pragma unroll
    for (int dt = 0; dt < 4; ++dt) {
      bf16x8 vF0 = *(const bf16x8*)&Vs[(dt * 16 + ln) * 72 + quad * 8];
      bf16x8 vF1 = *(const bf16x8*)&Vs[(dt * 16 + ln) * 72 + 32 + quad * 8];
      o[dt] = __builtin_amdgcn_mfma_f32_16x16x32_bf16(pF0, vF0, o[dt], 0, 0, 0);
      o[dt] = __builtin_amdgcn_mfma_f32_16x16x32_bf16(pF1, vF1, o[dt], 0, 0, 0);
    }
  }

  if (gid >= 1184 || !multi) {  // local + single-part global: direct write
#pragma unroll
    for (int dt = 0; dt < 4; ++dt)
#pragma unroll
      for (int rg = 0; rg < 4; ++rg) {
        int row = b * SQ + qb0 + wave * 16 + quad * 4 + rg;
        int e = h * 64 + dt * 16 + ln;
        AOut[(size_t)row * 768 + e] = bfbits(o[dt][rg] / ls[rg]);
      }
  } else {  // multi-part global: partials
#pragma unroll
    for (int dt = 0; dt < 4; ++dt)
#pragma unroll
      for (int rg = 0; rg < 4; ++rg) {
        int row = wave * 16 + quad * 4 + rg;
        Opart[(size_t)slot * 4096 + row * 64 + dt * 16 + ln] = bfbits(o[dt][rg]);
      }
    if (ln == 0) {
#pragma unroll
      for (int rg = 0; rg < 4; ++rg)
        Lpart[(size_t)slot * 64 + wave * 16 + quad * 4 + rg] = ls[rg];
    }
  }
}

// ---------------- combine split-K partials (global heads, qb>=9) -----------
__global__ __launch_bounds__(256) void combine_parts(
    const unsigned short* __restrict__ Opart, const float* __restrict__ Lpart,
    unsigned short* __restrict__ AOut) {
  const int bid = blockIdx.x;        // 368 = 16 bh * 23 (qb-9)
  const int bh = bid / 23, qb = bid % 23 + 9;
  const int b = bh >> 2, h = 8 + (bh & 3);
  const int np = qb / 9 + 1;
  const int t = threadIdx.x, r = t >> 2, c0 = (t & 3) * 16;
  const int slot0 = (bh * 32 + qb) * 4;
  float acc[16];
#pragma unroll
  for (int z = 0; z < 16; ++z) acc[z] = 0.f;
  float l = 0.f;
  for (int p = 0; p < np; ++p) {
    const unsigned short* src = &Opart[(size_t)(slot0 + p) * 4096 + r * 64 + c0];
    bf16x8 v0 = *(const bf16x8*)&src[0];
    bf16x8 v1 = *(const bf16x8*)&src[8];
#pragma unroll
    for (int z = 0; z < 8; ++z) { acc[z] += (float)v0[z]; acc[8 + z] += (float)v1[z]; }
    l += Lpart[(size_t)(slot0 + p) * 64 + r];
  }
  float inv = 1.f / l;
  unsigned short pk[16];
#pragma unroll
  for (int z = 0; z < 16; ++z) pk[z] = bfbits(acc[z] * inv);
  size_t dst = (size_t)(b * SQ + qb * 64 + r) * 768 + h * 64 + c0;
  *(uint4*)&AOut[dst]     = *(uint4*)&pk[0];
  *(uint4*)&AOut[dst + 8] = *(uint4*)&pk[8];
}

// ---------------- launch ----------------
extern "C" void kernel_launch(void* const* d_in, const int* in_sizes, int n_in,
                              void* d_out, int out_size, void* d_ws, size_t ws_size,
                              hipStream_t stream) {
  const float* x      = (const float*)d_in[0];
  const float* w_attn = (const float*)d_in[1];
  const float* b_attn = (const float*)d_in[2];
  const float* w_proj = (const float*)d_in[3];
  const float* b_proj = (const float*)d_in[4];
  float* out = (float*)d_out;

  char* ws = (char*)d_ws;
  size_t off = 0;
  auto alloc = [&](size_t bytes) {
    void* p = ws + off;
    off += (bytes + 255) & ~(size_t)255;
    return p;
  };
  unsigned short* xb     = (unsigned short*)alloc((size_t)8192 * 768 * 2);   // reused as attn buf
  unsigned short* wattnT = (unsigned short*)alloc((size_t)2304 * 768 * 2);
  unsigned short* wprojT = (unsigned short*)alloc((size_t)768 * 768 * 2);
  unsigned short* qkvb   = (unsigned short*)alloc((size_t)8192 * 2304 * 2);
  unsigned short* Vtb    = (unsigned short*)alloc((size_t)48 * 64 * 2048 * 2);
  unsigned short* Kgb    = (unsigned short*)alloc((size_t)16 * 256 * 64 * 2);
  unsigned short* VgTb   = (unsigned short*)alloc((size_t)16 * 64 * 256 * 2);
  int* gidxb             = (int*)alloc((size_t)256 * 4);
  unsigned short* Opartb = (unsigned short*)alloc((size_t)2048 * 4096 * 2);
  float* Lpartb          = (float*)alloc((size_t)2048 * 64 * 4);
  unsigned short* attnb  = xb;  // xb dead after qkv_gemm

  prep<<<dim3(512 + 72 * 24 + 24 * 24), dim3(256), 0, stream>>>(
      x, xb, w_attn, wattnT, w_proj, wprojT);
  qkv_gemm<<<dim3(36, 64), dim3(256), 0, stream>>>(xb, wattnT, b_attn, qkvb);
  vprep<<<dim3(1536 + 128), dim3(256), 0, stream>>>(qkvb, Vtb, Kgb, VgTb, gidxb);
  attn_kernel<<<dim3(2208), dim3(256), 0, stream>>>(qkvb, Vtb, Kgb, VgTb, gidxb,
                                                    attnb, Opartb, Lpartb);
  combine_parts<<<dim3(368), dim3(256), 0, stream>>>(Opartb, Lpartb, attnb);
  proj_gemm<<<dim3(12, 64), dim3(256), 0, stream>>>(attnb, wprojT, b_proj, out);
}

// Round 11
// 214.150 us; speedup vs baseline: 1.2833x; 1.0481x over previous
//
#include <hip/hip_runtime.h>
#include <stdint.h>

// SparseAttention MI355X bf16-MFMA pipeline. Output f32.
// QKV row-major [B*S][2304] bf16; V^T [B*H][64][2048] bf16 (vprep).
// Attention: CONSTANT-SHIFT softmax (p=exp(s-8), scores |s|<~3) -> partials
// over key-chunks are pure sums -> split-K for global heads + combine pass.
// R11: GEMMs back to BN=128 (BN=64 regressed qkv: <54.7 -> 59.6us) and BK=64
// via TWO unpadded 128x32 panels per operand: 12 K-iters, 32 MFMA/wave per
// barrier-pair (R5:16, R10:8), LDS 32KB (5 blocks/CU — m132's BK=128/64KB
// cliff avoided). attn = exact R5 structure (best measured 55us).
// MFMA 16x16x32 bf16 layouts (HW-verified): A[m=lane&15][k=quad*8+j],
// B[k=quad*8+j][n=lane&15], C/D col=lane&15 row=quad*4+reg.

#define NH 12
#define SQ 2048

typedef __bf16 bf16x8 __attribute__((ext_vector_type(8)));
typedef float f32x4 __attribute__((ext_vector_type(4)));

#define GLOAD_LDS16(g, l)                                                      \
  __builtin_amdgcn_global_load_lds(                                            \
      (__attribute__((address_space(1))) void*)(g),                            \
      (__attribute__((address_space(3))) void*)(l), 16, 0, 0)

__device__ __forceinline__ unsigned short bfbits(float f) {
  __bf16 h = (__bf16)f;
  return *(unsigned short*)&h;
}

// ---------------- prep: x->bf16 + both weight transposes (1 kernel) --------
__global__ __launch_bounds__(256) void prep(
    const float* __restrict__ x, unsigned short* __restrict__ xb,
    const float* __restrict__ w_attn, unsigned short* __restrict__ wattnT,
    const float* __restrict__ w_proj, unsigned short* __restrict__ wprojT) {
  const int bid = blockIdx.x, t = threadIdx.x;
  if (bid < 512) {                 // convert x: 8192*768 floats
    const int n4 = 8192 * 768 / 4;
    for (int i = bid * 256 + t; i < n4; i += 512 * 256) {
      float4 v = ((const float4*)x)[i];
      ((ushort4*)xb)[i] = make_ushort4(bfbits(v.x), bfbits(v.y), bfbits(v.z), bfbits(v.w));
    }
    return;
  }
  __shared__ float tile[32][33];
  const float* in; unsigned short* out; int K, N, tl;
  if (bid < 512 + 72 * 24) { in = w_attn; out = wattnT; K = 768; N = 2304; tl = bid - 512; }
  else                     { in = w_proj; out = wprojT; K = 768; N = 768;  tl = bid - 512 - 72 * 24; }
  const int tpr = N / 32;
  const int n0 = (tl % tpr) * 32, k0 = (tl / tpr) * 32;
  const int tx = t & 31, ty = t >> 5;
  for (int r = ty; r < 32; r += 8) tile[r][tx] = in[(size_t)(k0 + r) * N + n0 + tx];
  __syncthreads();
  for (int r = ty; r < 32; r += 8) out[(size_t)(n0 + r) * K + k0 + tx] = bfbits(tile[tx][r]);
}

// ---------------- vprep: V transpose + gcol gather (1 kernel) ----------------
__global__ __launch_bounds__(256) void vprep(const unsigned short* __restrict__ QKV,
                                             unsigned short* __restrict__ Vtb,
                                             unsigned short* __restrict__ Kg,
                                             unsigned short* __restrict__ VgT,
                                             int* __restrict__ gidx) {
  const int id = blockIdx.x, t = threadIdx.x;
  if (id < 1536) {                 // vtrans
    const int bh = id >> 5, b = bh / NH, h = bh % NH;
    const int s0 = (id & 31) * 64;
    __shared__ unsigned short T[64][72];
    const int r = t >> 2, c0 = (t & 3) * 16;
    const size_t src = (size_t)(b * SQ + s0 + r) * 2304 + 1536 + h * 64 + c0;
    *(uint4*)&T[r][c0]     = *(const uint4*)&QKV[src];
    *(uint4*)&T[r][c0 + 8] = *(const uint4*)&QKV[src + 8];
    __syncthreads();
    unsigned short pk[16];
#pragma unroll
    for (int z = 0; z < 16; ++z) pk[z] = T[c0 + z][r];
    size_t dst = (size_t)bh * 131072 + (size_t)r * 2048 + s0 + c0;
    *(uint4*)&Vtb[dst]     = *(uint4*)&pk[0];
    *(uint4*)&Vtb[dst + 8] = *(uint4*)&pk[8];
    return;
  }
  const int g = id - 1536;         // gather: 16 bh * 8 chunks
  const int bh = g >> 3, y = g & 7;
  const int b = bh >> 2, h = 8 + (bh & 3);
  if (g == 0) {
    int c = t;
    gidx[c] = (c < 203) ? (int)((double)c * (2047.0 / 203.0)) : ((c == 203) ? 2047 : -1);
  }
  {  // Kg rows from qkvb K-section
    int c = t, ch = y;
    int col = (c < 203) ? (int)((double)c * (2047.0 / 203.0)) : ((c == 203) ? 2047 : -1);
    uint4 v = {0u, 0u, 0u, 0u};
    if (col >= 0) v = *(const uint4*)&QKV[(size_t)(b * SQ + col) * 2304 + 768 + h * 64 + ch * 8];
    *(uint4*)&Kg[((size_t)bh * 256 + c) * 64 + ch * 8] = v;
  }
  {  // VgT directly from qkvb V-section (transpose gather)
    int d = t >> 2;
    int cb = (t & 3) * 64 + y * 8;
    for (int cc = 0; cc < 8; ++cc) {
      int c = cb + cc;
      int col = (c < 203) ? (int)((double)c * (2047.0 / 203.0)) : ((c == 203) ? 2047 : -1);
      unsigned short v = 0;
      if (col >= 0) v = QKV[(size_t)(b * SQ + col) * 2304 + 1536 + h * 64 + d];
      VgT[((size_t)bh * 64 + d) * 256 + c] = v;
    }
  }
}

// ------ GEMM mainloop (BM=BN=128, BK=64 via 2 panels, async LDS DMA) -------
// As/Bs: [2][128][32] bf16 unpadded panels (panel kh covers cols kh*32..+31).
__device__ __forceinline__ void gemm_mainloop(
    const unsigned short* __restrict__ A, const unsigned short* __restrict__ BT,
    int m0, int n0, int tid,
    unsigned short* As, unsigned short* Bs,
    f32x4 acc[4][4]) {
  const int lane = tid & 63, wave = tid >> 6;
  const int wm = wave >> 1, wn = wave & 1;
  const int ln = lane & 15, quad = lane >> 4;
  const int arow = wave * 16 + (lane >> 2);   // +p*64 : staged row
  const int acol = (lane & 3) * 8;            // element offset in 32-col panel

#pragma unroll
  for (int mi = 0; mi < 4; ++mi)
#pragma unroll
    for (int ni = 0; ni < 4; ++ni) acc[mi][ni] = (f32x4){0.f, 0.f, 0.f, 0.f};

  for (int kt = 0; kt < 12; ++kt) {
    const int k0 = kt * 64;
    __syncthreads();
#pragma unroll
    for (int p = 0; p < 2; ++p) {
      const int ldso = (p * 64 + wave * 16) * 32;
      GLOAD_LDS16(A  + (size_t)(m0 + p * 64 + arow) * 768 + k0 + acol,       &As[ldso]);
      GLOAD_LDS16(A  + (size_t)(m0 + p * 64 + arow) * 768 + k0 + 32 + acol,  &As[4096 + ldso]);
      GLOAD_LDS16(BT + (size_t)(n0 + p * 64 + arow) * 768 + k0 + acol,       &Bs[ldso]);
      GLOAD_LDS16(BT + (size_t)(n0 + p * 64 + arow) * 768 + k0 + 32 + acol,  &Bs[4096 + ldso]);
    }
    __syncthreads();
#pragma unroll
    for (int kh = 0; kh < 2; ++kh) {
      const int base = kh * 4096;
      bf16x8 aF[4], bF[4];
#pragma unroll
      for (int mi = 0; mi < 4; ++mi)
        aF[mi] = *(const bf16x8*)&As[base + (wm * 64 + mi * 16 + ln) * 32 + quad * 8];
#pragma unroll
      for (int ni = 0; ni < 4; ++ni)
        bF[ni] = *(const bf16x8*)&Bs[base + (wn * 64 + ni * 16 + ln) * 32 + quad * 8];
#pragma unroll
      for (int mi = 0; mi < 4; ++mi)
#pragma unroll
        for (int ni = 0; ni < 4; ++ni)
          acc[mi][ni] = __builtin_amdgcn_mfma_f32_16x16x32_bf16(aF[mi], bF[ni], acc[mi][ni], 0, 0, 0);
    }
  }
}

// ---------------- QKV GEMM: row-major bf16 out ----------------
__global__ __launch_bounds__(256) void qkv_gemm(
    const unsigned short* __restrict__ Xb, const unsigned short* __restrict__ WT,
    const float* __restrict__ bias, unsigned short* __restrict__ Out) {
  __shared__ __attribute__((aligned(16))) unsigned short As[2 * 128 * 32];
  __shared__ __attribute__((aligned(16))) unsigned short Bs[2 * 128 * 32];
  f32x4 acc[4][4];
  const int m0 = blockIdx.y * 128, n0 = blockIdx.x * 128;
  const int tid = threadIdx.x;
  gemm_mainloop(Xb, WT, m0, n0, tid, As, Bs, acc);
  const int lane = tid & 63, wave = tid >> 6;
  const int wm = wave >> 1, wn = wave & 1, ln = lane & 15, quad = lane >> 4;
#pragma unroll
  for (int mi = 0; mi < 4; ++mi)
#pragma unroll
    for (int ni = 0; ni < 4; ++ni) {
      int n = n0 + wn * 64 + ni * 16 + ln;
      float bs = bias[n];
#pragma unroll
      for (int rg = 0; rg < 4; ++rg) {
        int m = m0 + wm * 64 + mi * 16 + quad * 4 + rg;
        Out[(size_t)m * 2304 + n] = bfbits(acc[mi][ni][rg] + bs);
      }
    }
}

// ---------------- Proj GEMM: fp32 out ----------------
__global__ __launch_bounds__(256) void proj_gemm(
    const unsigned short* __restrict__ Ab, const unsigned short* __restrict__ WT,
    const float* __restrict__ bias, float* __restrict__ Out) {
  __shared__ __attribute__((aligned(16))) unsigned short As[2 * 128 * 32];
  __shared__ __attribute__((aligned(16))) unsigned short Bs[2 * 128 * 32];
  f32x4 acc[4][4];
  const int m0 = blockIdx.y * 128, n0 = blockIdx.x * 128;
  const int tid = threadIdx.x;
  gemm_mainloop(Ab, WT, m0, n0, tid, As, Bs, acc);
  const int lane = tid & 63, wave = tid >> 6;
  const int wm = wave >> 1, wn = wave & 1, ln = lane & 15, quad = lane >> 4;
#pragma unroll
  for (int mi = 0; mi < 4; ++mi)
#pragma unroll
    for (int ni = 0; ni < 4; ++ni)
#pragma unroll
      for (int rg = 0; rg < 4; ++rg) {
        int m = m0 + wm * 64 + mi * 16 + quad * 4 + rg;
        int n = n0 + wn * 64 + ni * 16 + ln;
        Out[(size_t)m * 768 + n] = acc[mi][ni][rg] + bias[n];
      }
}

// ---------------- Flash attention (exact R5 structure, best measured) ------
// Grid 2208: [0,1184) global-head parts (<=13 tiles), [1184,2208) local (<=5).
__global__ __launch_bounds__(256, 6) void attn_kernel(
    const unsigned short* __restrict__ QKV,   // [8192][2304]
    const unsigned short* __restrict__ Vtb,   // [48][64][2048]
    const unsigned short* __restrict__ Kg, const unsigned short* __restrict__ VgT,
    const int* __restrict__ gidx,
    unsigned short* __restrict__ AOut,        // [8192][768]
    unsigned short* __restrict__ Opart,       // [2048][4096] bf16
    float* __restrict__ Lpart) {              // [2048][64]
  __shared__ __attribute__((aligned(16))) unsigned short Ks[64 * 72];  // also P
  __shared__ __attribute__((aligned(16))) unsigned short Vs[64 * 72];

  const int gid = blockIdx.x;
  int b, h, qb, kb_begin, kb_end, slot = 0;
  bool do_g = false, multi = false;
  if (gid < 1184) {
    int bh = gid / 74, rem = gid % 74;
    b = bh >> 2; h = 8 + (bh & 3);
    int part;
    if (rem < 9)       { qb = rem; part = 0; }
    else if (rem < 27) { int z = rem - 9;  qb = 9 + (z >> 1);  part = z & 1; }
    else if (rem < 54) { int z = rem - 27; int q3 = z / 3; qb = 18 + q3; part = z - 3 * q3; }
    else               { int z = rem - 54; qb = 27 + (z >> 2); part = z & 3; }
    kb_begin = part * 9;
    kb_end = min(part * 9 + 8, qb);
    do_g = (part == 0);
    multi = (qb >= 9);
    slot = (bh * 32 + qb) * 4 + part;
  } else {
    int lid = gid - 1184;
    int bh = lid >> 5; b = bh >> 3; h = bh & 7; qb = lid & 31;
    kb_begin = (qb > 4) ? qb - 4 : 0; kb_end = qb;
  }
  const int qb0 = qb * 64;
  const bool is_local = (h < 8);
  const int tid = threadIdx.x, lane = tid & 63, wave = tid >> 6;
  const int ln = lane & 15, quad = lane >> 4;
  const int bh48 = b * NH + h;
  const int bhg = (b << 2) | (h & 3);

  const size_t qoff = (size_t)(b * SQ + qb0 + wave * 16 + ln) * 2304 + h * 64;
  bf16x8 qA0 = *(const bf16x8*)&QKV[qoff + quad * 8];
  bf16x8 qA1 = *(const bf16x8*)&QKV[qoff + 32 + quad * 8];

  bf16x8 onesF;
#pragma unroll
  for (int z = 0; z < 8; ++z) onesF[z] = (__bf16)1.0f;

  f32x4 o[4];
  f32x4 ls = (f32x4){0.f, 0.f, 0.f, 0.f};
#pragma unroll
  for (int dt = 0; dt < 4; ++dt) o[dt] = (f32x4){0.f, 0.f, 0.f, 0.f};

  const int nc = kb_end - kb_begin + 1;
  const int ntiles = nc + (do_g ? 4 : 0);
  const int irow = qb0 + wave * 16 + quad * 4;  // + rg
  const int iw = qb0 + wave * 16;
  const int sr = tid >> 3, sch = tid & 7;

  for (int t = 0; t < ntiles; ++t) {
    const bool gph = (t >= nc);
    const int kstart = gph ? 0 : (kb_begin + t) * 64;
    const int kg0 = gph ? (t - nc) * 64 : 0;
    __syncthreads();  // prev iter's P/Vs reads done before restage
    if (!gph) {
#pragma unroll
      for (int p = 0; p < 2; ++p) {
        int row = p * 32 + sr;
        *(uint4*)&Ks[row * 72 + sch * 8] =
            *(const uint4*)&QKV[(size_t)(b * SQ + kstart + row) * 2304 + 768 + h * 64 + sch * 8];
        *(uint4*)&Vs[row * 72 + sch * 8] =
            *(const uint4*)&Vtb[(size_t)bh48 * 131072 + (size_t)row * 2048 + kstart + sch * 8];
      }
    } else {
#pragma unroll
      for (int p = 0; p < 2; ++p) {
        int row = p * 32 + sr;
        *(uint4*)&Ks[row * 72 + sch * 8] =
            *(const uint4*)&Kg[((size_t)bhg * 256 + kg0 + row) * 64 + sch * 8];
        *(uint4*)&Vs[row * 72 + sch * 8] =
            *(const uint4*)&VgT[((size_t)bhg * 64 + row) * 256 + kg0 + sch * 8];
      }
    }
    __syncthreads();

    float sc[4][4];
    const bool full = !gph && (kstart + 63 <= iw) && (!is_local || kstart >= iw - 241);
#pragma unroll
    for (int nt = 0; nt < 4; ++nt) {
      bf16x8 kF0 = *(const bf16x8*)&Ks[(nt * 16 + ln) * 72 + quad * 8];
      bf16x8 kF1 = *(const bf16x8*)&Ks[(nt * 16 + ln) * 72 + 32 + quad * 8];
      f32x4 c = (f32x4){0.f, 0.f, 0.f, 0.f};
      c = __builtin_amdgcn_mfma_f32_16x16x32_bf16(qA0, kF0, c, 0, 0, 0);
      c = __builtin_amdgcn_mfma_f32_16x16x32_bf16(qA1, kF1, c, 0, 0, 0);
      if (full) {
#pragma unroll
        for (int rg = 0; rg < 4; ++rg) sc[nt][rg] = c[rg] * 0.125f - 8.f;
      } else if (!gph) {
        int j = kstart + nt * 16 + ln;
#pragma unroll
        for (int rg = 0; rg < 4; ++rg) {
          int i = irow + rg;
          bool ok = is_local ? (j >= i - 256 && j <= i) : (j <= i);
          sc[nt][rg] = ok ? (c[rg] * 0.125f - 8.f) : -1e9f;
        }
      } else {
        int jg = gidx[kg0 + nt * 16 + ln];
#pragma unroll
        for (int rg = 0; rg < 4; ++rg) {
          bool ok = jg > (irow + rg);
          sc[nt][rg] = ok ? (c[rg] * 0.125f - 8.f) : -1e9f;
        }
      }
    }
    __syncthreads();  // all waves done reading Ks -> reuse as P

    __bf16* P = (__bf16*)Ks;
#pragma unroll
    for (int rg = 0; rg < 4; ++rg) {
      int prow = (wave * 16 + quad * 4 + rg) * 72;
#pragma unroll
      for (int nt = 0; nt < 4; ++nt)
        P[prow + nt * 16 + ln] = (__bf16)__expf(sc[nt][rg]);
    }
    // same-wave LDS RAW (DS pipe in-order per wave) — no barrier needed
    bf16x8 pF0 = *(const bf16x8*)&Ks[(wave * 16 + ln) * 72 + quad * 8];
    bf16x8 pF1 = *(const bf16x8*)&Ks[(wave * 16 + ln) * 72 + 32 + quad * 8];
    ls = __builtin_amdgcn_mfma_f32_16x16x32_bf16(pF0, onesF, ls, 0, 0, 0);
    ls = __builtin_amdgcn_mfma_f32_16x16x32_bf16(pF1, onesF, ls, 0, 0, 0);
#pragma unroll
    for (int dt = 0; dt < 4; ++dt) {
      bf16x8 vF0 = *(const bf16x8*)&Vs[(dt * 16 + ln) * 72 + quad * 8];
      bf16x8 vF1 = *(const bf16x8*)&Vs[(dt * 16 + ln) * 72 + 32 + quad * 8];
      o[dt] = __builtin_amdgcn_mfma_f32_16x16x32_bf16(pF0, vF0, o[dt], 0, 0, 0);
      o[dt] = __builtin_amdgcn_mfma_f32_16x16x32_bf16(pF1, vF1, o[dt], 0, 0, 0);
    }
  }

  if (gid >= 1184 || !multi) {  // local + single-part global: direct write
#pragma unroll
    for (int dt = 0; dt < 4; ++dt)
#pragma unroll
      for (int rg = 0; rg < 4; ++rg) {
        int row = b * SQ + qb0 + wave * 16 + quad * 4 + rg;
        int e = h * 64 + dt * 16 + ln;
        AOut[(size_t)row * 768 + e] = bfbits(o[dt][rg] / ls[rg]);
      }
  } else {  // multi-part global: partials
#pragma unroll
    for (int dt = 0; dt < 4; ++dt)
#pragma unroll
      for (int rg = 0; rg < 4; ++rg) {
        int row = wave * 16 + quad * 4 + rg;
        Opart[(size_t)slot * 4096 + row * 64 + dt * 16 + ln] = bfbits(o[dt][rg]);
      }
    if (ln == 0) {
#pragma unroll
      for (int rg = 0; rg < 4; ++rg)
        Lpart[(size_t)slot * 64 + wave * 16 + quad * 4 + rg] = ls[rg];
    }
  }
}

// ---------------- combine split-K partials (global heads, qb>=9) -----------
__global__ __launch_bounds__(256) void combine_parts(
    const unsigned short* __restrict__ Opart, const float* __restrict__ Lpart,
    unsigned short* __restrict__ AOut) {
  const int bid = blockIdx.x;        // 368 = 16 bh * 23 (qb-9)
  const int bh = bid / 23, qb = bid % 23 + 9;
  const int b = bh >> 2, h = 8 + (bh & 3);
  const int np = qb / 9 + 1;
  const int t = threadIdx.x, r = t >> 2, c0 = (t & 3) * 16;
  const int slot0 = (bh * 32 + qb) * 4;
  float acc[16];
#pragma unroll
  for (int z = 0; z < 16; ++z) acc[z] = 0.f;
  float l = 0.f;
  for (int p = 0; p < np; ++p) {
    const unsigned short* src = &Opart[(size_t)(slot0 + p) * 4096 + r * 64 + c0];
    bf16x8 v0 = *(const bf16x8*)&src[0];
    bf16x8 v1 = *(const bf16x8*)&src[8];
#pragma unroll
    for (int z = 0; z < 8; ++z) { acc[z] += (float)v0[z]; acc[8 + z] += (float)v1[z]; }
    l += Lpart[(size_t)(slot0 + p) * 64 + r];
  }
  float inv = 1.f / l;
  unsigned short pk[16];
#pragma unroll
  for (int z = 0; z < 16; ++z) pk[z] = bfbits(acc[z] * inv);
  size_t dst = (size_t)(b * SQ + qb * 64 + r) * 768 + h * 64 + c0;
  *(uint4*)&AOut[dst]     = *(uint4*)&pk[0];
  *(uint4*)&AOut[dst + 8] = *(uint4*)&pk[8];
}

// ---------------- launch ----------------
extern "C" void kernel_launch(void* const* d_in, const int* in_sizes, int n_in,
                              void* d_out, int out_size, void* d_ws, size_t ws_size,
                              hipStream_t stream) {
  const float* x      = (const float*)d_in[0];
  const float* w_attn = (const float*)d_in[1];
  const float* b_attn = (const float*)d_in[2];
  const float* w_proj = (const float*)d_in[3];
  const float* b_proj = (const float*)d_in[4];
  float* out = (float*)d_out;

  char* ws = (char*)d_ws;
  size_t off = 0;
  auto alloc = [&](size_t bytes) {
    void* p = ws + off;
    off += (bytes + 255) & ~(size_t)255;
    return p;
  };
  unsigned short* xb     = (unsigned short*)alloc((size_t)8192 * 768 * 2);   // reused as attn buf
  unsigned short* wattnT = (unsigned short*)alloc((size_t)2304 * 768 * 2);
  unsigned short* wprojT = (unsigned short*)alloc((size_t)768 * 768 * 2);
  unsigned short* qkvb   = (unsigned short*)alloc((size_t)8192 * 2304 * 2);
  unsigned short* Vtb    = (unsigned short*)alloc((size_t)48 * 64 * 2048 * 2);
  unsigned short* Kgb    = (unsigned short*)alloc((size_t)16 * 256 * 64 * 2);
  unsigned short* VgTb   = (unsigned short*)alloc((size_t)16 * 64 * 256 * 2);
  int* gidxb             = (int*)alloc((size_t)256 * 4);
  unsigned short* Opartb = (unsigned short*)alloc((size_t)2048 * 4096 * 2);
  float* Lpartb          = (float*)alloc((size_t)2048 * 64 * 4);
  unsigned short* attnb  = xb;  // xb dead after qkv_gemm

  prep<<<dim3(512 + 72 * 24 + 24 * 24), dim3(256), 0, stream>>>(
      x, xb, w_attn, wattnT, w_proj, wprojT);
  qkv_gemm<<<dim3(18, 64), dim3(256), 0, stream>>>(xb, wattnT, b_attn, qkvb);
  vprep<<<dim3(1536 + 128), dim3(256), 0, stream>>>(qkvb, Vtb, Kgb, VgTb, gidxb);
  attn_kernel<<<dim3(2208), dim3(256), 0, stream>>>(qkvb, Vtb, Kgb, VgTb, gidxb,
                                                    attnb, Opartb, Lpartb);
  combine_parts<<<dim3(368), dim3(256), 0, stream>>>(Opartb, Lpartb, attnb);
  proj_gemm<<<dim3(6, 64), dim3(256), 0, stream>>>(attnb, wprojT, b_proj, out);
}